// Round 11
// baseline (729.072 us; speedup 1.0000x reference)
//
#include <hip/hip_runtime.h>
#include <cstdint>
#include <cstddef>

// Problem constants
#define NCH_CONST 16     // bucket = platform*16 + channel
#define SED 32           // encoded feature dim
#define HID 64           // tokenizer hidden dim
#define MLP_IN 33        // 1 + 28 meta + 4 emb
#define OUTD 512         // projection output dim

#define TILE3 192        // 3 slots per quad: rows s, s+64, s+128

__device__ __forceinline__ void fma4(float4& acc, float xk, float4 wv) {
    acc.x = fmaf(xk, wv.x, acc.x);
    acc.y = fmaf(xk, wv.y, acc.y);
    acc.z = fmaf(xk, wv.z, acc.z);
    acc.w = fmaf(xk, wv.w, acc.w);
}

__device__ __forceinline__ void atomAddF(float* p, float v) {
    unsafeAtomicAdd(p, v);   // native global_atomic_add_f32 (fallback path only)
}

// ===========================================================================
// K0: seg histogram pre-pass.
// ===========================================================================
__global__ __launch_bounds__(256) void seghist_kernel(
    const int* __restrict__ g_pix, const int* __restrict__ g_off,
    int* __restrict__ g_hist, int nobs, int npix, int nbatch)
{
    __shared__ int s_off[32];
    if (threadIdx.x < 32)
        s_off[threadIdx.x] = (threadIdx.x < nbatch) ? g_off[threadIdx.x] : 0x7fffffff;
    __syncthreads();
    const int i = blockIdx.x * 256 + threadIdx.x;
    if (i < nobs) {
        int bidx = 0;
        for (int j = 0; j < nbatch; ++j) bidx += (i >= s_off[j]) ? 1 : 0;
        if (bidx > nbatch - 1) bidx = nbatch - 1;
        atomicAdd(&g_hist[bidx * npix + g_pix[i]], 1);
    }
}

// ===========================================================================
// K1 (R20, unchanged — proven 414 us): 3 slots/quad, barrier-free per-wave
// ownership, issue-early/write-late staging, weights in LDS, packed segbid.
// ===========================================================================

#define P2S3(xa, xb, xc, K) {                                                  \
    const float4* wr = (const float4*)&s_w1p[(K)*64 + p*16];                   \
    float4 wa = wr[0], wb = wr[1], wc = wr[2], wd = wr[3];                     \
    fma4(hA0, (xa), wa); fma4(hA1, (xa), wb);                                  \
    fma4(hA2, (xa), wc); fma4(hA3, (xa), wd);                                  \
    fma4(hB0, (xb), wa); fma4(hB1, (xb), wb);                                  \
    fma4(hB2, (xb), wc); fma4(hB3, (xb), wd);                                  \
    fma4(hC0, (xc), wa); fma4(hC1, (xc), wb);                                  \
    fma4(hC2, (xc), wc); fma4(hC3, (xc), wd); }

#define P3S3(ha, hb, hc, K) {                                                  \
    const float4* wr = (const float4*)&s_w2s[(K)*32 + p*8];                    \
    float4 wa = wr[0], wb = wr[1];                                             \
    fma4(yA0, (ha), wa); fma4(yA1, (ha), wb);                                  \
    fma4(yB0, (hb), wa); fma4(yB1, (hb), wb);                                  \
    fma4(yC0, (hc), wa); fma4(yC1, (hc), wb); }

#define STG_LOAD(TT) {                                                         \
    const int mA = (((TT) * TILE3) + rowA0) * 28;                              \
    _Pragma("unroll")                                                          \
    for (int g = 0; g < 3; ++g) {                                              \
        const int mb = mA + g * (64*28);                                       \
        _Pragma("unroll")                                                      \
        for (int i = 0; i < 7; ++i) {                                          \
            const int j = mb + lane + (i << 6);                                \
            pfm[g][i] = (j < nmeta) ? g_meta[j] : 0.f;                         \
        }                                                                      \
    }                                                                          \
    if (lane < 48) {                                                           \
        const int rr = rowA0 + ((lane >> 4) << 6) + (lane & 15);               \
        const int gi = (TT) * TILE3 + rr;                                      \
        const bool v = gi < nobs;                                              \
        pf_o = v ? g_obs[gi] : 0.f;                                            \
        const int ot = v ? g_otype[gi] : 0;                                    \
        pf_e = ((const float4*)g_embed)[ot];                                   \
        const int px = v ? g_pix[gi] : 0;                                      \
        const int pl = v ? g_lplat[gi] : 0;                                    \
        const int lc = v ? g_lch[gi] : 0;                                      \
        int bidx = 0;                                                          \
        for (int j2 = 0; j2 < nbatch; ++j2) bidx += (gi >= s_off[j2]) ? 1 : 0; \
        if (bidx > nbatch - 1) bidx = nbatch - 1;                              \
        pf_seg = bidx * npix + px;                                             \
        pf_bid = pl * NCH_CONST + lc;                                          \
        pf_rr = rr;                                                            \
    }                                                                          \
}

#define STG_WRITE() {                                                          \
    _Pragma("unroll")                                                          \
    for (int g = 0; g < 3; ++g) {                                              \
        const int rb = rowA0 + (g << 6);                                       \
        _Pragma("unroll")                                                      \
        for (int i = 0; i < 7; ++i) {                                          \
            const int ii = lane + (i << 6);                                    \
            const int sl = ii / 28, cc = ii - sl * 28;                         \
            s_XH[(rb + sl) * 68 + cc] = pfm[g][i];                             \
        }                                                                      \
    }                                                                          \
    if (lane < 48) {                                                           \
        s_XH[pf_rr * 68 + 32] = pf_o;                                          \
        *(float4*)&s_XH[pf_rr * 68 + 28] = pf_e;                               \
        s_segbid[pf_rr] = pf_seg | (pf_bid << 18);                             \
    }                                                                          \
}

__global__ __launch_bounds__(256, 2) void mlp_encode_kernel(
    const float* __restrict__ g_obs,
    const float* __restrict__ g_meta,
    const int*   __restrict__ g_pix,
    const int*   __restrict__ g_lch,
    const int*   __restrict__ g_lplat,
    const int*   __restrict__ g_otype,
    const int*   __restrict__ g_off,
    const float* __restrict__ g_embed,
    const float* __restrict__ g_w1,
    const float* __restrict__ g_b1,
    const float* __restrict__ g_lng,
    const float* __restrict__ g_lnb,
    const float* __restrict__ g_w2,
    const float* __restrict__ g_b2,
    const float* __restrict__ g_bucket,
    float* __restrict__ g_enc,      // (nobs, 32) SORTED-position encoded rows
    int*   __restrict__ g_cursor,   // (nseg,) = base after scan; bumped here
    int nobs, int npix, int nbatch)
{
    __shared__ __align__(16) float s_w1p[MLP_IN*HID]; // 8448 B, PERMUTED rows
    __shared__ __align__(16) float s_w2s[HID*32];     // shifted, 8192 B
    __shared__ __align__(16) float s_b1[HID];
    __shared__ __align__(16) float s_g[HID];
    __shared__ __align__(16) float s_lb[HID];
    __shared__ __align__(16) float s_b2s[32];         // shifted b2 (c0 = 0)
    __shared__ int   s_off[32];
    __shared__ int   s_segbid[TILE3];                 // seg | (bid<<18)
    __shared__ __align__(16) float s_XH[TILE3*68];    // X(33u)/H(64u) overlay

    const int t = threadIdx.x;

    for (int i = t; i < MLP_IN*HID; i += 256) {
        const int c = i >> 6, j = i & 63;
        const int kp = (c == 32) ? 0 : (c + 1);  // meta c->w1 row c+1; obs(32)->row 0
        s_w1p[i] = g_w1[kp*64 + j];
    }
    for (int i = t; i < HID*32; i += 256) {
        int k = i >> 5, c = i & 31;
        s_w2s[i] = (c == 0) ? 0.0f : g_w2[k*31 + (c-1)];
    }
    if (t < HID) { s_b1[t] = g_b1[t]; s_g[t] = g_lng[t]; s_lb[t] = g_lnb[t]; }
    if (t < 32)  {
        s_b2s[t] = (t == 0) ? 0.0f : g_b2[t-1];
        s_off[t] = (t < nbatch) ? g_off[t] : 0x7fffffff;
    }
    __syncthreads();   // the ONLY barrier

    const int w = t >> 6;        // wave id (0..3)
    const int lane = t & 63;
    const int s = t >> 2;        // slot group; wave w owns s in [16w,16w+16)
    const int p = t & 3;         // part (h[16p..16p+15], enc ch [8p,8p+8))
    const int rowA0 = w << 4;
    const int ntiles = (nobs + TILE3 - 1) / TILE3;
    const int stride = gridDim.x;
    const int nmeta = nobs * 28;

    float pfm[3][7];
    float pf_o = 0.f;
    float4 pf_e = make_float4(0.f, 0.f, 0.f, 0.f);
    int pf_seg = 0, pf_bid = 0, pf_rr = 0;

    int tile = blockIdx.x;
    if (tile < ntiles) {
        STG_LOAD(tile)
        STG_WRITE()
    }

    for (; tile < ntiles; tile += stride) {
        const int nt = tile + stride;
        const bool has_next = nt < ntiles;
        if (has_next) STG_LOAD(nt)

        const int base = tile * TILE3;

        float4 hA0 = ((const float4*)s_b1)[p*4+0];
        float4 hA1 = ((const float4*)s_b1)[p*4+1];
        float4 hA2 = ((const float4*)s_b1)[p*4+2];
        float4 hA3 = ((const float4*)s_b1)[p*4+3];
        float4 hB0 = hA0, hB1 = hA1, hB2 = hA2, hB3 = hA3;
        float4 hC0 = hA0, hC1 = hA1, hC2 = hA2, hC3 = hA3;
        const float* xrowA = &s_XH[s*68];
        const float* xrowB = &s_XH[(s+64)*68];
        const float* xrowC = &s_XH[(s+128)*68];
        const float oA = xrowA[32];
        const float oB = xrowB[32];
        const float oC = xrowC[32];
        #pragma unroll 4
        for (int k4 = 0; k4 < 8; ++k4) {
            const float4 xvA = ((const float4*)xrowA)[k4];
            const float4 xvB = ((const float4*)xrowB)[k4];
            const float4 xvC = ((const float4*)xrowC)[k4];
            const int kb = k4 * 4;
            P2S3(xvA.x, xvB.x, xvC.x, kb+0)
            P2S3(xvA.y, xvB.y, xvC.y, kb+1)
            P2S3(xvA.z, xvB.z, xvC.z, kb+2)
            P2S3(xvA.w, xvB.w, xvC.w, kb+3)
        }
        P2S3(oA, oB, oC, 32)

        #define HS4(h0,h1,h2,h3) ((h0.x+h0.y+h0.z+h0.w)+(h1.x+h1.y+h1.z+h1.w)+ \
                                  (h2.x+h2.y+h2.z+h2.w)+(h3.x+h3.y+h3.z+h3.w))
        float muA = HS4(hA0,hA1,hA2,hA3);
        float muB = HS4(hB0,hB1,hB2,hB3);
        float muC = HS4(hC0,hC1,hC2,hC3);
        #undef HS4
        muA += __shfl_xor(muA, 1, 64); muB += __shfl_xor(muB, 1, 64);
        muC += __shfl_xor(muC, 1, 64);
        muA += __shfl_xor(muA, 2, 64); muB += __shfl_xor(muB, 2, 64);
        muC += __shfl_xor(muC, 2, 64);
        muA *= (1.f/64.f); muB *= (1.f/64.f); muC *= (1.f/64.f);
        #define SQS(hh, mm) ((hh.x-mm)*(hh.x-mm)+(hh.y-mm)*(hh.y-mm)+ \
                             (hh.z-mm)*(hh.z-mm)+(hh.w-mm)*(hh.w-mm))
        float varA = SQS(hA0,muA) + SQS(hA1,muA) + SQS(hA2,muA) + SQS(hA3,muA);
        float varB = SQS(hB0,muB) + SQS(hB1,muB) + SQS(hB2,muB) + SQS(hB3,muB);
        float varC = SQS(hC0,muC) + SQS(hC1,muC) + SQS(hC2,muC) + SQS(hC3,muC);
        #undef SQS
        varA += __shfl_xor(varA, 1, 64); varB += __shfl_xor(varB, 1, 64);
        varC += __shfl_xor(varC, 1, 64);
        varA += __shfl_xor(varA, 2, 64); varB += __shfl_xor(varB, 2, 64);
        varC += __shfl_xor(varC, 2, 64);
        const float rsA = rsqrtf(varA*(1.f/64.f) + 1e-5f);
        const float rsB = rsqrtf(varB*(1.f/64.f) + 1e-5f);
        const float rsC = rsqrtf(varC*(1.f/64.f) + 1e-5f);

        const float4* g4 = (const float4*)&s_g[p*16];
        const float4* l4 = (const float4*)&s_lb[p*16];
        float4 ga = g4[0], gb = g4[1], gc = g4[2], gd = g4[3];
        float4 la = l4[0], lb_ = l4[1], lc = l4[2], ld = l4[3];
        #define LNSILU(hh, mm, rr, gg, ll) { \
            float v0 = (hh.x - mm) * rr * gg.x + ll.x; \
            float v1 = (hh.y - mm) * rr * gg.y + ll.y; \
            float v2 = (hh.z - mm) * rr * gg.z + ll.z; \
            float v3 = (hh.w - mm) * rr * gg.w + ll.w; \
            hh.x = v0 / (1.f + __expf(-v0)); \
            hh.y = v1 / (1.f + __expf(-v1)); \
            hh.z = v2 / (1.f + __expf(-v2)); \
            hh.w = v3 / (1.f + __expf(-v3)); }
        LNSILU(hA0, muA, rsA, ga, la); LNSILU(hA1, muA, rsA, gb, lb_);
        LNSILU(hA2, muA, rsA, gc, lc); LNSILU(hA3, muA, rsA, gd, ld);
        LNSILU(hB0, muB, rsB, ga, la); LNSILU(hB1, muB, rsB, gb, lb_);
        LNSILU(hB2, muB, rsB, gc, lc); LNSILU(hB3, muB, rsB, gd, ld);
        LNSILU(hC0, muC, rsC, ga, la); LNSILU(hC1, muC, rsC, gb, lb_);
        LNSILU(hC2, muC, rsC, gc, lc); LNSILU(hC3, muC, rsC, gd, ld);
        #undef LNSILU

        float4* hdstA = (float4*)&s_XH[s*68 + p*16];
        hdstA[0] = hA0; hdstA[1] = hA1; hdstA[2] = hA2; hdstA[3] = hA3;
        float4* hdstB = (float4*)&s_XH[(s+64)*68 + p*16];
        hdstB[0] = hB0; hdstB[1] = hB1; hdstB[2] = hB2; hdstB[3] = hB3;
        float4* hdstC = (float4*)&s_XH[(s+128)*68 + p*16];
        hdstC[0] = hC0; hdstC[1] = hC1; hdstC[2] = hC2; hdstC[3] = hC3;

        float4 yA0 = ((const float4*)s_b2s)[p*2+0];
        float4 yA1 = ((const float4*)s_b2s)[p*2+1];
        float4 yB0 = yA0, yB1 = yA1;
        float4 yC0 = yA0, yC1 = yA1;
        const float* hrowA = &s_XH[s*68];
        const float* hrowB = &s_XH[(s+64)*68];
        const float* hrowC = &s_XH[(s+128)*68];
        #pragma unroll 4
        for (int k4 = 0; k4 < 16; ++k4) {
            const float4 hvA = ((const float4*)hrowA)[k4];
            const float4 hvB = ((const float4*)hrowB)[k4];
            const float4 hvC = ((const float4*)hrowC)[k4];
            const int kb = k4 * 4;
            P3S3(hvA.x, hvB.x, hvC.x, kb+0)
            P3S3(hvA.y, hvB.y, hvC.y, kb+1)
            P3S3(hvA.z, hvB.z, hvC.z, kb+2)
            P3S3(hvA.w, hvB.w, hvC.w, kb+3)
        }

        const int giA = base + s;
        const int giB = giA + 64;
        const int giC = giA + 128;
        int posA = 0, posB = 0, posC = 0;
        if (p == 0) {
            if (giA < nobs) posA = atomicAdd(&g_cursor[s_segbid[s] & 0x3FFFF], 1);
            if (giB < nobs) posB = atomicAdd(&g_cursor[s_segbid[s+64] & 0x3FFFF], 1);
            if (giC < nobs) posC = atomicAdd(&g_cursor[s_segbid[s+128] & 0x3FFFF], 1);
        }
        posA = __shfl(posA, lane & ~3, 64);
        posB = __shfl(posB, lane & ~3, 64);
        posC = __shfl(posC, lane & ~3, 64);

        if (giA < nobs) {
            const float4* bkt = (const float4*)g_bucket + (s_segbid[s] >> 18)*8;
            float4 ba = bkt[p*2], bb = bkt[p*2+1];
            if (p == 0) yA0.x = oA;
            float4 r0 = make_float4(yA0.x+ba.x, yA0.y+ba.y, yA0.z+ba.z, yA0.w+ba.w);
            float4 r1 = make_float4(yA1.x+bb.x, yA1.y+bb.y, yA1.z+bb.z, yA1.w+bb.w);
            float4* dst = (float4*)(g_enc + (size_t)posA * SED + p*8);
            dst[0] = r0; dst[1] = r1;
        }
        if (giB < nobs) {
            const float4* bkt = (const float4*)g_bucket + (s_segbid[s+64] >> 18)*8;
            float4 ba = bkt[p*2], bb = bkt[p*2+1];
            if (p == 0) yB0.x = oB;
            float4 r0 = make_float4(yB0.x+ba.x, yB0.y+ba.y, yB0.z+ba.z, yB0.w+ba.w);
            float4 r1 = make_float4(yB1.x+bb.x, yB1.y+bb.y, yB1.z+bb.z, yB1.w+bb.w);
            float4* dst = (float4*)(g_enc + (size_t)posB * SED + p*8);
            dst[0] = r0; dst[1] = r1;
        }
        if (giC < nobs) {
            const float4* bkt = (const float4*)g_bucket + (s_segbid[s+128] >> 18)*8;
            float4 ba = bkt[p*2], bb = bkt[p*2+1];
            if (p == 0) yC0.x = oC;
            float4 r0 = make_float4(yC0.x+ba.x, yC0.y+ba.y, yC0.z+ba.z, yC0.w+ba.w);
            float4 r1 = make_float4(yC1.x+bb.x, yC1.y+bb.y, yC1.z+bb.z, yC1.w+bb.w);
            float4* dst = (float4*)(g_enc + (size_t)posC * SED + p*8);
            dst[0] = r0; dst[1] = r1;
        }

        if (has_next) STG_WRITE()
    }
}

// ---------------------------------------------------------------------------
// K2a: per-block exclusive scan of hist (512 elems/block), RAW block totals
// ---------------------------------------------------------------------------
__global__ __launch_bounds__(256) void scan_block_kernel(
    const int* __restrict__ g_hist, int* __restrict__ g_base,
    int* __restrict__ g_btot, int n)
{
    __shared__ int s[512];
    const int t  = threadIdx.x;
    const int i0 = blockIdx.x * 512 + t;
    const int i1 = i0 + 256;
    const int o0 = (i0 < n) ? g_hist[i0] : 0;
    const int o1 = (i1 < n) ? g_hist[i1] : 0;
    s[t] = o0; s[t+256] = o1;
    __syncthreads();
    for (int off = 1; off < 512; off <<= 1) {
        int a = (t >= off) ? s[t - off] : 0;
        int b = s[t + 256 - off];
        __syncthreads();
        s[t] += a; s[t+256] += b;
        __syncthreads();
    }
    if (i0 < n) g_base[i0] = s[t] - o0;
    if (i1 < n) g_base[i1] = s[t+256] - o1;
    if (t == 255) g_btot[blockIdx.x] = s[511];
}

// ---------------------------------------------------------------------------
// K2b: add_spine with INLINE spine prefix (kills scan_spine launch).
// ---------------------------------------------------------------------------
__global__ __launch_bounds__(256) void add_spine_kernel(
    int* __restrict__ g_base, int* __restrict__ g_cursor,
    const int* __restrict__ g_btot, int nblocksScan, int n)
{
    __shared__ int s[256];
    const int t = threadIdx.x;
    const int sb = blockIdx.x >> 1;       // scan-block covering this add-block
    s[t] = (t < sb && t < nblocksScan) ? g_btot[t] : 0;
    __syncthreads();
    for (int off = 128; off > 0; off >>= 1) {
        if (t < off) s[t] += s[t + off];
        __syncthreads();
    }
    const int prefix = s[0];
    const int i = blockIdx.x * 256 + t;
    if (i < n) {
        int v = g_base[i] + prefix;
        g_base[i] = v;
        g_cursor[i] = v;
    }
}

// ---------------------------------------------------------------------------
// K4+K5 fused (R22): reduce 16 segments -> s_cell (threads 0-127) while
// threads 128-255 stage wp; proj phase TRANSPOSED: thread owns one output
// column c4 (t&127) and 8 cells — one w read feeds 8 cells (was 1), cutting
// proj LDS reads 256 b128 + 256 b32 -> 96 b128 per 8 outputs (~4x fewer
// LDS-pipe cycles; R21 tail analysis: proj LDS serialization ~165 us).
// Cell reads are wave-uniform broadcasts; w reads stride-16B (conflict-free).
// ---------------------------------------------------------------------------
#define CG 16
__device__ __forceinline__ void add4(float4& a, float4 b) {
    a.x += b.x; a.y += b.y; a.z += b.z; a.w += b.w;
}

__global__ __launch_bounds__(256) void reduce_proj_kernel(
    const float* __restrict__ g_enc,
    const int*   __restrict__ g_base,
    const int*   __restrict__ g_hist,
    const float* __restrict__ g_infill,
    const float* __restrict__ g_wp,
    const float* __restrict__ g_bp,
    float* __restrict__ g_out,
    int nseg)
{
    __shared__ __align__(16) float s_wp[SED*OUTD];    // 65536 B
    __shared__ __align__(16) float s_cell[CG][SED];   // 2048 B

    const int t = threadIdx.x;
    const int cell0 = blockIdx.x * CG;

    if (t < 128) {
        // ---- reduce phase: 16 segs x 8 lanes ----
        const int gl = t >> 3;            // local segment 0..15
        const int c4r = t & 7;            // float4 column
        const int g  = cell0 + gl;
        float4 r = make_float4(0,0,0,0);
        if (g < nseg) {
            const int b = g_base[g];
            const int n = g_hist[g];
            const float4* src = (const float4*)g_enc + (size_t)b * 8 + c4r;
            float4 a0 = make_float4(0,0,0,0), a1 = a0, a2 = a0, a3 = a0;
            int j = 0;
            for (; j + 3 < n; j += 4) {
                float4 v0 = src[(size_t)(j+0)*8];
                float4 v1 = src[(size_t)(j+1)*8];
                float4 v2 = src[(size_t)(j+2)*8];
                float4 v3 = src[(size_t)(j+3)*8];
                add4(a0, v0); add4(a1, v1); add4(a2, v2); add4(a3, v3);
            }
            for (; j < n; ++j) add4(a0, src[(size_t)j*8]);
            add4(a0, a1); add4(a2, a3); add4(a0, a2);
            if (n > 0) {
                const float inv = 1.f / (float)n;
                r = make_float4(a0.x*inv, a0.y*inv, a0.z*inv, a0.w*inv);
            } else {
                r = ((const float4*)g_infill)[c4r];
            }
        }
        *(float4*)&s_cell[gl][c4r*4] = r;
    } else {
        // ---- wp staging: 128 threads copy 4096 float4 (64 KB) ----
        const int t2 = t - 128;
        #pragma unroll
        for (int i = 0; i < 32; ++i) {
            const int idx = t2 + i*128;
            ((float4*)s_wp)[idx] = ((const float4*)g_wp)[idx];
        }
    }
    __syncthreads();

    // ---- proj phase (transposed): thread owns col c4, cells g0..g0+7 ----
    const int c4 = t & 127;
    const int g0 = (t >> 7) * 8;          // 0 or 8
    const float4 bpv = ((const float4*)g_bp)[c4];
    float4 acc[8];
    #pragma unroll
    for (int i = 0; i < 8; ++i) acc[i] = bpv;

    #pragma unroll
    for (int k4 = 0; k4 < 8; ++k4) {
        const int kb = k4 * 4;
        const float4 w0 = ((const float4*)s_wp)[(kb+0)*128 + c4];
        const float4 w1 = ((const float4*)s_wp)[(kb+1)*128 + c4];
        const float4 w2 = ((const float4*)s_wp)[(kb+2)*128 + c4];
        const float4 w3 = ((const float4*)s_wp)[(kb+3)*128 + c4];
        float4 cv[8];
        #pragma unroll
        for (int i = 0; i < 8; ++i)
            cv[i] = *(const float4*)&s_cell[g0 + i][kb];
        #pragma unroll
        for (int i = 0; i < 8; ++i) {
            fma4(acc[i], cv[i].x, w0);
            fma4(acc[i], cv[i].y, w1);
            fma4(acc[i], cv[i].z, w2);
            fma4(acc[i], cv[i].w, w3);
        }
    }

    #pragma unroll
    for (int i = 0; i < 8; ++i) {
        const int g = cell0 + g0 + i;
        if (g < nseg)
            ((float4*)g_out)[(size_t)g * 128 + c4] = acc[i];
    }
}

// ===========================================================================
// FALLBACK (ws too small or nseg too large for packed segbid): atomic path
// ===========================================================================
__global__ __launch_bounds__(256, 2) void tok_scatter_kernel(
    const float* __restrict__ g_obs, const float* __restrict__ g_meta,
    const int* __restrict__ g_pix, const int* __restrict__ g_lch,
    const int* __restrict__ g_lplat, const int* __restrict__ g_otype,
    const int* __restrict__ g_off, const float* __restrict__ g_embed,
    const float* __restrict__ g_w1, const float* __restrict__ g_b1,
    const float* __restrict__ g_lng, const float* __restrict__ g_lnb,
    const float* __restrict__ g_w2, const float* __restrict__ g_b2,
    const float* __restrict__ g_bucket,
    float* __restrict__ g_sums, float* __restrict__ g_cnts,
    int nobs, int npix, int nbatch)
{
    __shared__ __align__(16) float s_w1[MLP_IN*HID];
    __shared__ __align__(16) float s_w2s[HID*32];
    __shared__ __align__(16) float s_b1[HID], s_g[HID], s_lb[HID];
    __shared__ __align__(16) float s_b2s[32];
    __shared__ int   s_off[32];
    __shared__ __align__(16) float s_X[64*34];
    __shared__ __align__(16) float s_H[64*68];

    const int t = threadIdx.x;
    for (int i = t; i < MLP_IN*HID; i += 256) s_w1[i] = g_w1[i];
    for (int i = t; i < HID*32; i += 256) {
        int k = i >> 5, c = i & 31;
        s_w2s[i] = (c == 0) ? 0.0f : g_w2[k*31 + (c-1)];
    }
    if (t < HID) { s_b1[t] = g_b1[t]; s_g[t] = g_lng[t]; s_lb[t] = g_lnb[t]; }
    if (t < 32)  {
        s_b2s[t] = (t == 0) ? 0.0f : g_b2[t-1];
        s_off[t] = (t < nbatch) ? g_off[t] : 0x7fffffff;
    }
    __syncthreads();

    const int s = t >> 2;
    const int p = t & 3;
    const int ntiles = (nobs + 63) >> 6;

    for (int tile = blockIdx.x; tile < ntiles; tile += gridDim.x) {
        const int base = tile << 6;
        for (int j = t; j < 64*28; j += 256) {
            int sl = j / 28, c = j - sl*28;
            float v = ((base + sl) < nobs) ? g_meta[(size_t)base*28 + j] : 0.f;
            s_X[sl*34 + 1 + c] = v;
        }
        if (t < 64) {
            const int gi = base + t;
            float o = 0.f; int ot = 0;
            if (gi < nobs) { o = g_obs[gi]; ot = g_otype[gi]; }
            s_X[t*34 + 0] = o;
            float4 e = ((const float4*)g_embed)[ot];
            s_X[t*34 + 29] = e.x; s_X[t*34 + 30] = e.y;
            s_X[t*34 + 31] = e.z; s_X[t*34 + 32] = e.w;
        }
        __syncthreads();

        float4 h0 = ((const float4*)s_b1)[p*4+0];
        float4 h1 = ((const float4*)s_b1)[p*4+1];
        float4 h2 = ((const float4*)s_b1)[p*4+2];
        float4 h3 = ((const float4*)s_b1)[p*4+3];
        const float* xrow = &s_X[s*34];
        #pragma unroll 2
        for (int k = 0; k < MLP_IN; ++k) {
            const float xk = xrow[k];
            const float4* wr = (const float4*)&s_w1[k*64 + p*16];
            float4 wa = wr[0], wb = wr[1], wc = wr[2], wd = wr[3];
            fma4(h0, xk, wa); fma4(h1, xk, wb);
            fma4(h2, xk, wc); fma4(h3, xk, wd);
        }
        float mu = (h0.x+h0.y+h0.z+h0.w) + (h1.x+h1.y+h1.z+h1.w)
                 + (h2.x+h2.y+h2.z+h2.w) + (h3.x+h3.y+h3.z+h3.w);
        mu += __shfl_xor(mu, 1, 64);
        mu += __shfl_xor(mu, 2, 64);
        mu *= (1.f/64.f);
        float var =
            (h0.x-mu)*(h0.x-mu)+(h0.y-mu)*(h0.y-mu)+(h0.z-mu)*(h0.z-mu)+(h0.w-mu)*(h0.w-mu)
          + (h1.x-mu)*(h1.x-mu)+(h1.y-mu)*(h1.y-mu)+(h1.z-mu)*(h1.z-mu)+(h1.w-mu)*(h1.w-mu)
          + (h2.x-mu)*(h2.x-mu)+(h2.y-mu)*(h2.y-mu)+(h2.z-mu)*(h2.z-mu)+(h2.w-mu)*(h2.w-mu)
          + (h3.x-mu)*(h3.x-mu)+(h3.y-mu)*(h3.y-mu)+(h3.z-mu)*(h3.z-mu)+(h3.w-mu)*(h3.w-mu);
        var += __shfl_xor(var, 1, 64);
        var += __shfl_xor(var, 2, 64);
        var *= (1.f/64.f);
        const float rs = rsqrtf(var + 1e-5f);
        const float4* g4 = (const float4*)&s_g[p*16];
        const float4* l4 = (const float4*)&s_lb[p*16];
        float4 ga = g4[0], gb = g4[1], gc = g4[2], gd = g4[3];
        float4 la = l4[0], lb_ = l4[1], lc = l4[2], ld = l4[3];
        #define LNSILU(hh, gg, ll) { \
            float v0 = (hh.x - mu) * rs * gg.x + ll.x; \
            float v1 = (hh.y - mu) * rs * gg.y + ll.y; \
            float v2 = (hh.z - mu) * rs * gg.z + ll.z; \
            float v3 = (hh.w - mu) * rs * gg.w + ll.w; \
            hh.x = v0 / (1.f + __expf(-v0)); \
            hh.y = v1 / (1.f + __expf(-v1)); \
            hh.z = v2 / (1.f + __expf(-v2)); \
            hh.w = v3 / (1.f + __expf(-v3)); }
        LNSILU(h0, ga, la); LNSILU(h1, gb, lb_);
        LNSILU(h2, gc, lc); LNSILU(h3, gd, ld);
        #undef LNSILU
        float4* hdst = (float4*)&s_H[s*68 + p*16];
        hdst[0] = h0; hdst[1] = h1; hdst[2] = h2; hdst[3] = h3;
        __syncthreads();

        float4 y0 = ((const float4*)s_b2s)[p*2+0];
        float4 y1 = ((const float4*)s_b2s)[p*2+1];
        const float* hrow = &s_H[s*68];
        #pragma unroll 2
        for (int k = 0; k < HID; ++k) {
            const float hk = hrow[k];
            const float4* wr = (const float4*)&s_w2s[k*32 + p*8];
            float4 wa = wr[0], wb = wr[1];
            fma4(y0, hk, wa); fma4(y1, hk, wb);
        }
        const int gi = base + s;
        if (gi < nobs) {
            int bidx = 0;
            for (int j2 = 0; j2 < nbatch; ++j2) bidx += (gi >= s_off[j2]) ? 1 : 0;
            if (bidx > nbatch - 1) bidx = nbatch - 1;
            const int seg = bidx * npix + g_pix[gi];
            const int bid = g_lplat[gi] * NCH_CONST + g_lch[gi];
            const float4* bkt = (const float4*)g_bucket + bid*8;
            float4 ba = bkt[p*2], bb = bkt[p*2+1];
            if (p == 0) y0.x = s_X[s*34];
            float* sp = g_sums + (size_t)seg * SED + p*8;
            atomAddF(&sp[0], y0.x+ba.x); atomAddF(&sp[1], y0.y+ba.y);
            atomAddF(&sp[2], y0.z+ba.z); atomAddF(&sp[3], y0.w+ba.w);
            atomAddF(&sp[4], y1.x+bb.x); atomAddF(&sp[5], y1.y+bb.y);
            atomAddF(&sp[6], y1.z+bb.z); atomAddF(&sp[7], y1.w+bb.w);
            if (p == 0) atomAddF(&g_cnts[seg], 1.0f);
        }
        __syncthreads();
    }
}

__global__ __launch_bounds__(256) void proj_meancnt_kernel(
    const float* __restrict__ g_sums, const float* __restrict__ g_cnts,
    const float* __restrict__ g_infill, const float* __restrict__ g_wp,
    const float* __restrict__ g_bp, float* __restrict__ g_out, int nseg)
{
    __shared__ __align__(16) float s_wp[SED*256];
    __shared__ __align__(16) float s_cell[CG][SED];
    const int t = threadIdx.x;
    const int half = blockIdx.y;
    const int cell0 = blockIdx.x * CG;
    for (int i = t; i < SED*64; i += 256) {
        int k = i >> 6, c4 = i & 63;
        ((float4*)s_wp)[k*64 + c4] = ((const float4*)g_wp)[k*128 + half*64 + c4];
    }
    for (int i = t; i < CG*SED; i += 256) {
        int g = i >> 5, c = i & 31;
        float cnt = g_cnts[cell0 + g];
        float s   = g_sums[(size_t)(cell0 + g)*SED + c];
        s_cell[g][c] = (cnt > 0.f) ? (s / fmaxf(cnt, 1.f)) : g_infill[c];
    }
    __syncthreads();
    #pragma unroll
    for (int it = 0; it < 4; ++it) {
        int idx4 = it*256 + t;
        int g  = idx4 >> 6;
        int c4 = idx4 & 63;
        float4 acc = ((const float4*)g_bp)[half*64 + c4];
        #pragma unroll
        for (int k = 0; k < SED; ++k) {
            float cg = s_cell[g][k];
            float4 w = ((const float4*)s_wp)[k*64 + c4];
            acc.x += cg*w.x; acc.y += cg*w.y; acc.z += cg*w.z; acc.w += cg*w.w;
        }
        ((float4*)g_out)[(size_t)(cell0 + g)*128 + half*64 + c4] = acc;
    }
}

// ===========================================================================
extern "C" void kernel_launch(void* const* d_in, const int* in_sizes, int n_in,
                              void* d_out, int out_size, void* d_ws, size_t ws_size,
                              hipStream_t stream)
{
    const float* obs    = (const float*)d_in[0];
    const float* meta   = (const float*)d_in[1];
    const int*   pix    = (const int*)d_in[2];
    const int*   lch    = (const int*)d_in[3];
    const int*   lplat  = (const int*)d_in[4];
    const int*   otype  = (const int*)d_in[5];
    const int*   offs   = (const int*)d_in[6];
    const float* embed  = (const float*)d_in[8];
    const float* w1     = (const float*)d_in[9];
    const float* b1     = (const float*)d_in[10];
    const float* lng    = (const float*)d_in[11];
    const float* lnb    = (const float*)d_in[12];
    const float* w2     = (const float*)d_in[13];
    const float* b2     = (const float*)d_in[14];
    const float* bucket = (const float*)d_in[15];
    const float* infill = (const float*)d_in[16];
    const float* wp     = (const float*)d_in[17];
    const float* bp     = (const float*)d_in[18];

    const int nobs   = in_sizes[0];
    const int nbatch = in_sizes[6];
    const int npix   = out_size / (nbatch * OUTD);
    const int nseg   = nbatch * npix;

    // ---- workspace layout (bytes) ----
    char* w = (char*)d_ws;
    size_t off = 0;
    int*   hist    = (int*)(w + off);   off += (size_t)nseg * 4;
    int*   base    = (int*)(w + off);   off += (size_t)nseg * 4;
    int*   cursor  = (int*)(w + off);   off += (size_t)nseg * 4;
    int*   btot    = (int*)(w + off);   off += 4096;
    float* enc     = (float*)(w + off); off += (size_t)nobs * SED * 4;
    const size_t need = off;

    const int ntiles     = (nobs + TILE3 - 1) / TILE3;
    const int gridMlp    = (ntiles < 2048) ? ntiles : 2048;
    const int blocksScan = (nseg + 511) / 512;   // must be <= 256

    if (ws_size >= need && blocksScan <= 256 && nseg <= (1 << 18)) {
        // ---- fast path: hist -> scan -> sorted-write MLP -> fused reduce+proj
        hipMemsetAsync(hist, 0, (size_t)nseg * 4, stream);

        seghist_kernel<<<(nobs + 255)/256, 256, 0, stream>>>(
            pix, offs, hist, nobs, npix, nbatch);

        scan_block_kernel<<<blocksScan, 256, 0, stream>>>(hist, base, btot, nseg);
        add_spine_kernel<<<(nseg + 255)/256, 256, 0, stream>>>(
            base, cursor, btot, blocksScan, nseg);

        mlp_encode_kernel<<<gridMlp, 256, 0, stream>>>(
            obs, meta, pix, lch, lplat, otype, offs,
            embed, w1, b1, lng, lnb, w2, b2, bucket,
            enc, cursor, nobs, npix, nbatch);

        reduce_proj_kernel<<<(nseg + CG - 1)/CG, 256, 0, stream>>>(
            enc, base, hist, infill, wp, bp, (float*)d_out, nseg);
    } else {
        // ---------------- fallback: atomic path ----------------
        float* sums = (float*)d_ws;
        float* cnts = sums + (size_t)nseg * SED;
        hipMemsetAsync(d_ws, 0, (size_t)nseg * (SED + 1) * sizeof(float), stream);
        const int ntiles64 = (nobs + 63) / 64;
        const int gridTok  = (ntiles64 < 2048) ? ntiles64 : 2048;
        tok_scatter_kernel<<<gridTok, 256, 0, stream>>>(
            obs, meta, pix, lch, lplat, otype, offs,
            embed, w1, b1, lng, lnb, w2, b2, bucket,
            sums, cnts, nobs, npix, nbatch);
        dim3 gp((nseg + CG - 1)/CG, 2, 1);
        proj_meancnt_kernel<<<gp, 256, 0, stream>>>(sums, cnts, infill, wp, bp,
                                                    (float*)d_out, nseg);
    }
}

// Round 12
// 648.893 us; speedup vs baseline: 1.1236x; 1.1236x over previous
//
#include <hip/hip_runtime.h>
#include <cstdint>
#include <cstddef>

// Problem constants
#define NCH_CONST 16     // bucket = platform*16 + channel
#define SED 32           // encoded feature dim
#define HID 64           // tokenizer hidden dim
#define MLP_IN 33        // 1 + 28 meta + 4 emb
#define OUTD 512         // projection output dim

#define TILE3 192        // 3 slots per quad: rows s, s+64, s+128

__device__ __forceinline__ void fma4(float4& acc, float xk, float4 wv) {
    acc.x = fmaf(xk, wv.x, acc.x);
    acc.y = fmaf(xk, wv.y, acc.y);
    acc.z = fmaf(xk, wv.z, acc.z);
    acc.w = fmaf(xk, wv.w, acc.w);
}

__device__ __forceinline__ void atomAddF(float* p, float v) {
    unsafeAtomicAdd(p, v);   // native global_atomic_add_f32 (fallback path only)
}

// ===========================================================================
// K0: seg histogram pre-pass.
// ===========================================================================
__global__ __launch_bounds__(256) void seghist_kernel(
    const int* __restrict__ g_pix, const int* __restrict__ g_off,
    int* __restrict__ g_hist, int nobs, int npix, int nbatch)
{
    __shared__ int s_off[32];
    if (threadIdx.x < 32)
        s_off[threadIdx.x] = (threadIdx.x < nbatch) ? g_off[threadIdx.x] : 0x7fffffff;
    __syncthreads();
    const int i = blockIdx.x * 256 + threadIdx.x;
    if (i < nobs) {
        int bidx = 0;
        for (int j = 0; j < nbatch; ++j) bidx += (i >= s_off[j]) ? 1 : 0;
        if (bidx > nbatch - 1) bidx = nbatch - 1;
        atomicAdd(&g_hist[bidx * npix + g_pix[i]], 1);
    }
}

// ===========================================================================
// K1 (R20, unchanged — proven 414 us): 3 slots/quad, barrier-free per-wave
// ownership, issue-early/write-late staging, weights in LDS, packed segbid.
// ===========================================================================

#define P2S3(xa, xb, xc, K) {                                                  \
    const float4* wr = (const float4*)&s_w1p[(K)*64 + p*16];                   \
    float4 wa = wr[0], wb = wr[1], wc = wr[2], wd = wr[3];                     \
    fma4(hA0, (xa), wa); fma4(hA1, (xa), wb);                                  \
    fma4(hA2, (xa), wc); fma4(hA3, (xa), wd);                                  \
    fma4(hB0, (xb), wa); fma4(hB1, (xb), wb);                                  \
    fma4(hB2, (xb), wc); fma4(hB3, (xb), wd);                                  \
    fma4(hC0, (xc), wa); fma4(hC1, (xc), wb);                                  \
    fma4(hC2, (xc), wc); fma4(hC3, (xc), wd); }

#define P3S3(ha, hb, hc, K) {                                                  \
    const float4* wr = (const float4*)&s_w2s[(K)*32 + p*8];                    \
    float4 wa = wr[0], wb = wr[1];                                             \
    fma4(yA0, (ha), wa); fma4(yA1, (ha), wb);                                  \
    fma4(yB0, (hb), wa); fma4(yB1, (hb), wb);                                  \
    fma4(yC0, (hc), wa); fma4(yC1, (hc), wb); }

#define STG_LOAD(TT) {                                                         \
    const int mA = (((TT) * TILE3) + rowA0) * 28;                              \
    _Pragma("unroll")                                                          \
    for (int g = 0; g < 3; ++g) {                                              \
        const int mb = mA + g * (64*28);                                       \
        _Pragma("unroll")                                                      \
        for (int i = 0; i < 7; ++i) {                                          \
            const int j = mb + lane + (i << 6);                                \
            pfm[g][i] = (j < nmeta) ? g_meta[j] : 0.f;                         \
        }                                                                      \
    }                                                                          \
    if (lane < 48) {                                                           \
        const int rr = rowA0 + ((lane >> 4) << 6) + (lane & 15);               \
        const int gi = (TT) * TILE3 + rr;                                      \
        const bool v = gi < nobs;                                              \
        pf_o = v ? g_obs[gi] : 0.f;                                            \
        const int ot = v ? g_otype[gi] : 0;                                    \
        pf_e = ((const float4*)g_embed)[ot];                                   \
        const int px = v ? g_pix[gi] : 0;                                      \
        const int pl = v ? g_lplat[gi] : 0;                                    \
        const int lc = v ? g_lch[gi] : 0;                                      \
        int bidx = 0;                                                          \
        for (int j2 = 0; j2 < nbatch; ++j2) bidx += (gi >= s_off[j2]) ? 1 : 0; \
        if (bidx > nbatch - 1) bidx = nbatch - 1;                              \
        pf_seg = bidx * npix + px;                                             \
        pf_bid = pl * NCH_CONST + lc;                                          \
        pf_rr = rr;                                                            \
    }                                                                          \
}

#define STG_WRITE() {                                                          \
    _Pragma("unroll")                                                          \
    for (int g = 0; g < 3; ++g) {                                              \
        const int rb = rowA0 + (g << 6);                                       \
        _Pragma("unroll")                                                      \
        for (int i = 0; i < 7; ++i) {                                          \
            const int ii = lane + (i << 6);                                    \
            const int sl = ii / 28, cc = ii - sl * 28;                         \
            s_XH[(rb + sl) * 68 + cc] = pfm[g][i];                             \
        }                                                                      \
    }                                                                          \
    if (lane < 48) {                                                           \
        s_XH[pf_rr * 68 + 32] = pf_o;                                          \
        *(float4*)&s_XH[pf_rr * 68 + 28] = pf_e;                               \
        s_segbid[pf_rr] = pf_seg | (pf_bid << 18);                             \
    }                                                                          \
}

__global__ __launch_bounds__(256, 2) void mlp_encode_kernel(
    const float* __restrict__ g_obs,
    const float* __restrict__ g_meta,
    const int*   __restrict__ g_pix,
    const int*   __restrict__ g_lch,
    const int*   __restrict__ g_lplat,
    const int*   __restrict__ g_otype,
    const int*   __restrict__ g_off,
    const float* __restrict__ g_embed,
    const float* __restrict__ g_w1,
    const float* __restrict__ g_b1,
    const float* __restrict__ g_lng,
    const float* __restrict__ g_lnb,
    const float* __restrict__ g_w2,
    const float* __restrict__ g_b2,
    const float* __restrict__ g_bucket,
    float* __restrict__ g_enc,      // (nobs, 32) SORTED-position encoded rows
    int*   __restrict__ g_cursor,   // (nseg,) = base after scan; bumped here
    int nobs, int npix, int nbatch)
{
    __shared__ __align__(16) float s_w1p[MLP_IN*HID]; // 8448 B, PERMUTED rows
    __shared__ __align__(16) float s_w2s[HID*32];     // shifted, 8192 B
    __shared__ __align__(16) float s_b1[HID];
    __shared__ __align__(16) float s_g[HID];
    __shared__ __align__(16) float s_lb[HID];
    __shared__ __align__(16) float s_b2s[32];         // shifted b2 (c0 = 0)
    __shared__ int   s_off[32];
    __shared__ int   s_segbid[TILE3];                 // seg | (bid<<18)
    __shared__ __align__(16) float s_XH[TILE3*68];    // X(33u)/H(64u) overlay

    const int t = threadIdx.x;

    for (int i = t; i < MLP_IN*HID; i += 256) {
        const int c = i >> 6, j = i & 63;
        const int kp = (c == 32) ? 0 : (c + 1);  // meta c->w1 row c+1; obs(32)->row 0
        s_w1p[i] = g_w1[kp*64 + j];
    }
    for (int i = t; i < HID*32; i += 256) {
        int k = i >> 5, c = i & 31;
        s_w2s[i] = (c == 0) ? 0.0f : g_w2[k*31 + (c-1)];
    }
    if (t < HID) { s_b1[t] = g_b1[t]; s_g[t] = g_lng[t]; s_lb[t] = g_lnb[t]; }
    if (t < 32)  {
        s_b2s[t] = (t == 0) ? 0.0f : g_b2[t-1];
        s_off[t] = (t < nbatch) ? g_off[t] : 0x7fffffff;
    }
    __syncthreads();   // the ONLY barrier

    const int w = t >> 6;        // wave id (0..3)
    const int lane = t & 63;
    const int s = t >> 2;        // slot group; wave w owns s in [16w,16w+16)
    const int p = t & 3;         // part (h[16p..16p+15], enc ch [8p,8p+8))
    const int rowA0 = w << 4;
    const int ntiles = (nobs + TILE3 - 1) / TILE3;
    const int stride = gridDim.x;
    const int nmeta = nobs * 28;

    float pfm[3][7];
    float pf_o = 0.f;
    float4 pf_e = make_float4(0.f, 0.f, 0.f, 0.f);
    int pf_seg = 0, pf_bid = 0, pf_rr = 0;

    int tile = blockIdx.x;
    if (tile < ntiles) {
        STG_LOAD(tile)
        STG_WRITE()
    }

    for (; tile < ntiles; tile += stride) {
        const int nt = tile + stride;
        const bool has_next = nt < ntiles;
        if (has_next) STG_LOAD(nt)

        const int base = tile * TILE3;

        float4 hA0 = ((const float4*)s_b1)[p*4+0];
        float4 hA1 = ((const float4*)s_b1)[p*4+1];
        float4 hA2 = ((const float4*)s_b1)[p*4+2];
        float4 hA3 = ((const float4*)s_b1)[p*4+3];
        float4 hB0 = hA0, hB1 = hA1, hB2 = hA2, hB3 = hA3;
        float4 hC0 = hA0, hC1 = hA1, hC2 = hA2, hC3 = hA3;
        const float* xrowA = &s_XH[s*68];
        const float* xrowB = &s_XH[(s+64)*68];
        const float* xrowC = &s_XH[(s+128)*68];
        const float oA = xrowA[32];
        const float oB = xrowB[32];
        const float oC = xrowC[32];
        #pragma unroll 4
        for (int k4 = 0; k4 < 8; ++k4) {
            const float4 xvA = ((const float4*)xrowA)[k4];
            const float4 xvB = ((const float4*)xrowB)[k4];
            const float4 xvC = ((const float4*)xrowC)[k4];
            const int kb = k4 * 4;
            P2S3(xvA.x, xvB.x, xvC.x, kb+0)
            P2S3(xvA.y, xvB.y, xvC.y, kb+1)
            P2S3(xvA.z, xvB.z, xvC.z, kb+2)
            P2S3(xvA.w, xvB.w, xvC.w, kb+3)
        }
        P2S3(oA, oB, oC, 32)

        #define HS4(h0,h1,h2,h3) ((h0.x+h0.y+h0.z+h0.w)+(h1.x+h1.y+h1.z+h1.w)+ \
                                  (h2.x+h2.y+h2.z+h2.w)+(h3.x+h3.y+h3.z+h3.w))
        float muA = HS4(hA0,hA1,hA2,hA3);
        float muB = HS4(hB0,hB1,hB2,hB3);
        float muC = HS4(hC0,hC1,hC2,hC3);
        #undef HS4
        muA += __shfl_xor(muA, 1, 64); muB += __shfl_xor(muB, 1, 64);
        muC += __shfl_xor(muC, 1, 64);
        muA += __shfl_xor(muA, 2, 64); muB += __shfl_xor(muB, 2, 64);
        muC += __shfl_xor(muC, 2, 64);
        muA *= (1.f/64.f); muB *= (1.f/64.f); muC *= (1.f/64.f);
        #define SQS(hh, mm) ((hh.x-mm)*(hh.x-mm)+(hh.y-mm)*(hh.y-mm)+ \
                             (hh.z-mm)*(hh.z-mm)+(hh.w-mm)*(hh.w-mm))
        float varA = SQS(hA0,muA) + SQS(hA1,muA) + SQS(hA2,muA) + SQS(hA3,muA);
        float varB = SQS(hB0,muB) + SQS(hB1,muB) + SQS(hB2,muB) + SQS(hB3,muB);
        float varC = SQS(hC0,muC) + SQS(hC1,muC) + SQS(hC2,muC) + SQS(hC3,muC);
        #undef SQS
        varA += __shfl_xor(varA, 1, 64); varB += __shfl_xor(varB, 1, 64);
        varC += __shfl_xor(varC, 1, 64);
        varA += __shfl_xor(varA, 2, 64); varB += __shfl_xor(varB, 2, 64);
        varC += __shfl_xor(varC, 2, 64);
        const float rsA = rsqrtf(varA*(1.f/64.f) + 1e-5f);
        const float rsB = rsqrtf(varB*(1.f/64.f) + 1e-5f);
        const float rsC = rsqrtf(varC*(1.f/64.f) + 1e-5f);

        const float4* g4 = (const float4*)&s_g[p*16];
        const float4* l4 = (const float4*)&s_lb[p*16];
        float4 ga = g4[0], gb = g4[1], gc = g4[2], gd = g4[3];
        float4 la = l4[0], lb_ = l4[1], lc = l4[2], ld = l4[3];
        #define LNSILU(hh, mm, rr, gg, ll) { \
            float v0 = (hh.x - mm) * rr * gg.x + ll.x; \
            float v1 = (hh.y - mm) * rr * gg.y + ll.y; \
            float v2 = (hh.z - mm) * rr * gg.z + ll.z; \
            float v3 = (hh.w - mm) * rr * gg.w + ll.w; \
            hh.x = v0 / (1.f + __expf(-v0)); \
            hh.y = v1 / (1.f + __expf(-v1)); \
            hh.z = v2 / (1.f + __expf(-v2)); \
            hh.w = v3 / (1.f + __expf(-v3)); }
        LNSILU(hA0, muA, rsA, ga, la); LNSILU(hA1, muA, rsA, gb, lb_);
        LNSILU(hA2, muA, rsA, gc, lc); LNSILU(hA3, muA, rsA, gd, ld);
        LNSILU(hB0, muB, rsB, ga, la); LNSILU(hB1, muB, rsB, gb, lb_);
        LNSILU(hB2, muB, rsB, gc, lc); LNSILU(hB3, muB, rsB, gd, ld);
        LNSILU(hC0, muC, rsC, ga, la); LNSILU(hC1, muC, rsC, gb, lb_);
        LNSILU(hC2, muC, rsC, gc, lc); LNSILU(hC3, muC, rsC, gd, ld);
        #undef LNSILU

        float4* hdstA = (float4*)&s_XH[s*68 + p*16];
        hdstA[0] = hA0; hdstA[1] = hA1; hdstA[2] = hA2; hdstA[3] = hA3;
        float4* hdstB = (float4*)&s_XH[(s+64)*68 + p*16];
        hdstB[0] = hB0; hdstB[1] = hB1; hdstB[2] = hB2; hdstB[3] = hB3;
        float4* hdstC = (float4*)&s_XH[(s+128)*68 + p*16];
        hdstC[0] = hC0; hdstC[1] = hC1; hdstC[2] = hC2; hdstC[3] = hC3;

        float4 yA0 = ((const float4*)s_b2s)[p*2+0];
        float4 yA1 = ((const float4*)s_b2s)[p*2+1];
        float4 yB0 = yA0, yB1 = yA1;
        float4 yC0 = yA0, yC1 = yA1;
        const float* hrowA = &s_XH[s*68];
        const float* hrowB = &s_XH[(s+64)*68];
        const float* hrowC = &s_XH[(s+128)*68];
        #pragma unroll 4
        for (int k4 = 0; k4 < 16; ++k4) {
            const float4 hvA = ((const float4*)hrowA)[k4];
            const float4 hvB = ((const float4*)hrowB)[k4];
            const float4 hvC = ((const float4*)hrowC)[k4];
            const int kb = k4 * 4;
            P3S3(hvA.x, hvB.x, hvC.x, kb+0)
            P3S3(hvA.y, hvB.y, hvC.y, kb+1)
            P3S3(hvA.z, hvB.z, hvC.z, kb+2)
            P3S3(hvA.w, hvB.w, hvC.w, kb+3)
        }

        const int giA = base + s;
        const int giB = giA + 64;
        const int giC = giA + 128;
        int posA = 0, posB = 0, posC = 0;
        if (p == 0) {
            if (giA < nobs) posA = atomicAdd(&g_cursor[s_segbid[s] & 0x3FFFF], 1);
            if (giB < nobs) posB = atomicAdd(&g_cursor[s_segbid[s+64] & 0x3FFFF], 1);
            if (giC < nobs) posC = atomicAdd(&g_cursor[s_segbid[s+128] & 0x3FFFF], 1);
        }
        posA = __shfl(posA, lane & ~3, 64);
        posB = __shfl(posB, lane & ~3, 64);
        posC = __shfl(posC, lane & ~3, 64);

        if (giA < nobs) {
            const float4* bkt = (const float4*)g_bucket + (s_segbid[s] >> 18)*8;
            float4 ba = bkt[p*2], bb = bkt[p*2+1];
            if (p == 0) yA0.x = oA;
            float4 r0 = make_float4(yA0.x+ba.x, yA0.y+ba.y, yA0.z+ba.z, yA0.w+ba.w);
            float4 r1 = make_float4(yA1.x+bb.x, yA1.y+bb.y, yA1.z+bb.z, yA1.w+bb.w);
            float4* dst = (float4*)(g_enc + (size_t)posA * SED + p*8);
            dst[0] = r0; dst[1] = r1;
        }
        if (giB < nobs) {
            const float4* bkt = (const float4*)g_bucket + (s_segbid[s+64] >> 18)*8;
            float4 ba = bkt[p*2], bb = bkt[p*2+1];
            if (p == 0) yB0.x = oB;
            float4 r0 = make_float4(yB0.x+ba.x, yB0.y+ba.y, yB0.z+ba.z, yB0.w+ba.w);
            float4 r1 = make_float4(yB1.x+bb.x, yB1.y+bb.y, yB1.z+bb.z, yB1.w+bb.w);
            float4* dst = (float4*)(g_enc + (size_t)posB * SED + p*8);
            dst[0] = r0; dst[1] = r1;
        }
        if (giC < nobs) {
            const float4* bkt = (const float4*)g_bucket + (s_segbid[s+128] >> 18)*8;
            float4 ba = bkt[p*2], bb = bkt[p*2+1];
            if (p == 0) yC0.x = oC;
            float4 r0 = make_float4(yC0.x+ba.x, yC0.y+ba.y, yC0.z+ba.z, yC0.w+ba.w);
            float4 r1 = make_float4(yC1.x+bb.x, yC1.y+bb.y, yC1.z+bb.z, yC1.w+bb.w);
            float4* dst = (float4*)(g_enc + (size_t)posC * SED + p*8);
            dst[0] = r0; dst[1] = r1;
        }

        if (has_next) STG_WRITE()
    }
}

// ---------------------------------------------------------------------------
// K2a: per-block exclusive scan of hist (512 elems/block), RAW block totals
// ---------------------------------------------------------------------------
__global__ __launch_bounds__(256) void scan_block_kernel(
    const int* __restrict__ g_hist, int* __restrict__ g_base,
    int* __restrict__ g_btot, int n)
{
    __shared__ int s[512];
    const int t  = threadIdx.x;
    const int i0 = blockIdx.x * 512 + t;
    const int i1 = i0 + 256;
    const int o0 = (i0 < n) ? g_hist[i0] : 0;
    const int o1 = (i1 < n) ? g_hist[i1] : 0;
    s[t] = o0; s[t+256] = o1;
    __syncthreads();
    for (int off = 1; off < 512; off <<= 1) {
        int a = (t >= off) ? s[t - off] : 0;
        int b = s[t + 256 - off];
        __syncthreads();
        s[t] += a; s[t+256] += b;
        __syncthreads();
    }
    if (i0 < n) g_base[i0] = s[t] - o0;
    if (i1 < n) g_base[i1] = s[t+256] - o1;
    if (t == 255) g_btot[blockIdx.x] = s[511];
}

// ---------------------------------------------------------------------------
// K2b: add_spine with INLINE spine prefix (kills scan_spine launch).
// ---------------------------------------------------------------------------
__global__ __launch_bounds__(256) void add_spine_kernel(
    int* __restrict__ g_base, int* __restrict__ g_cursor,
    const int* __restrict__ g_btot, int nblocksScan, int n)
{
    __shared__ int s[256];
    const int t = threadIdx.x;
    const int sb = blockIdx.x >> 1;       // scan-block covering this add-block
    s[t] = (t < sb && t < nblocksScan) ? g_btot[t] : 0;
    __syncthreads();
    for (int off = 128; off > 0; off >>= 1) {
        if (t < off) s[t] += s[t + off];
        __syncthreads();
    }
    const int prefix = s[0];
    const int i = blockIdx.x * 256 + t;
    if (i < n) {
        int v = g_base[i] + prefix;
        g_base[i] = v;
        g_cursor[i] = v;
    }
}

// ---------------------------------------------------------------------------
// K4+K5 fused (R21 proj, PROVEN — R22's transposed variant regressed +81 us;
// compiler LICM already hoists the it-invariant w reads): reduce 16 segments
// -> s_cell (threads 0-127) while threads 128-255 stage wp into LDS; then
// all 256 threads project the 16x512 output tile.
// ---------------------------------------------------------------------------
#define CG 16
__device__ __forceinline__ void add4(float4& a, float4 b) {
    a.x += b.x; a.y += b.y; a.z += b.z; a.w += b.w;
}

__global__ __launch_bounds__(256) void reduce_proj_kernel(
    const float* __restrict__ g_enc,
    const int*   __restrict__ g_base,
    const int*   __restrict__ g_hist,
    const float* __restrict__ g_infill,
    const float* __restrict__ g_wp,
    const float* __restrict__ g_bp,
    float* __restrict__ g_out,
    int nseg)
{
    __shared__ __align__(16) float s_wp[SED*OUTD];    // 65536 B
    __shared__ __align__(16) float s_cell[CG][SED];   // 2048 B

    const int t = threadIdx.x;
    const int cell0 = blockIdx.x * CG;

    if (t < 128) {
        // ---- reduce phase: 16 segs x 8 lanes ----
        const int gl = t >> 3;            // local segment 0..15
        const int c4 = t & 7;             // float4 column
        const int g  = cell0 + gl;
        float4 r = make_float4(0,0,0,0);
        if (g < nseg) {
            const int b = g_base[g];
            const int n = g_hist[g];
            const float4* src = (const float4*)g_enc + (size_t)b * 8 + c4;
            float4 a0 = make_float4(0,0,0,0), a1 = a0, a2 = a0, a3 = a0;
            int j = 0;
            for (; j + 3 < n; j += 4) {
                float4 v0 = src[(size_t)(j+0)*8];
                float4 v1 = src[(size_t)(j+1)*8];
                float4 v2 = src[(size_t)(j+2)*8];
                float4 v3 = src[(size_t)(j+3)*8];
                add4(a0, v0); add4(a1, v1); add4(a2, v2); add4(a3, v3);
            }
            for (; j < n; ++j) add4(a0, src[(size_t)j*8]);
            add4(a0, a1); add4(a2, a3); add4(a0, a2);
            if (n > 0) {
                const float inv = 1.f / (float)n;
                r = make_float4(a0.x*inv, a0.y*inv, a0.z*inv, a0.w*inv);
            } else {
                r = ((const float4*)g_infill)[c4];
            }
        }
        *(float4*)&s_cell[gl][c4*4] = r;
    } else {
        // ---- wp staging phase: 128 threads copy 4096 float4 (64 KB) ----
        const int t2 = t - 128;
        #pragma unroll
        for (int i = 0; i < 32; ++i) {
            const int idx = t2 + i*128;
            ((float4*)s_wp)[idx] = ((const float4*)g_wp)[idx];
        }
    }
    __syncthreads();

    // ---- proj phase: 16 cells x 128 float4 cols = 2048 float4; 8/thread ----
    #pragma unroll
    for (int it = 0; it < 8; ++it) {
        const int idx4 = it*256 + t;
        const int g  = idx4 >> 7;         // 0..15
        const int c4 = idx4 & 127;        // 0..127
        if (cell0 + g < nseg) {
            float4 acc = ((const float4*)g_bp)[c4];
            #pragma unroll
            for (int k = 0; k < SED; ++k) {
                const float cg = s_cell[g][k];
                const float4 w = ((const float4*)s_wp)[k*128 + c4];
                acc.x += cg*w.x; acc.y += cg*w.y; acc.z += cg*w.z; acc.w += cg*w.w;
            }
            ((float4*)g_out)[(size_t)(cell0 + g)*128 + c4] = acc;
        }
    }
}

// ===========================================================================
// FALLBACK (ws too small or nseg too large for packed segbid): atomic path
// ===========================================================================
__global__ __launch_bounds__(256, 2) void tok_scatter_kernel(
    const float* __restrict__ g_obs, const float* __restrict__ g_meta,
    const int* __restrict__ g_pix, const int* __restrict__ g_lch,
    const int* __restrict__ g_lplat, const int* __restrict__ g_otype,
    const int* __restrict__ g_off, const float* __restrict__ g_embed,
    const float* __restrict__ g_w1, const float* __restrict__ g_b1,
    const float* __restrict__ g_lng, const float* __restrict__ g_lnb,
    const float* __restrict__ g_w2, const float* __restrict__ g_b2,
    const float* __restrict__ g_bucket,
    float* __restrict__ g_sums, float* __restrict__ g_cnts,
    int nobs, int npix, int nbatch)
{
    __shared__ __align__(16) float s_w1[MLP_IN*HID];
    __shared__ __align__(16) float s_w2s[HID*32];
    __shared__ __align__(16) float s_b1[HID], s_g[HID], s_lb[HID];
    __shared__ __align__(16) float s_b2s[32];
    __shared__ int   s_off[32];
    __shared__ __align__(16) float s_X[64*34];
    __shared__ __align__(16) float s_H[64*68];

    const int t = threadIdx.x;
    for (int i = t; i < MLP_IN*HID; i += 256) s_w1[i] = g_w1[i];
    for (int i = t; i < HID*32; i += 256) {
        int k = i >> 5, c = i & 31;
        s_w2s[i] = (c == 0) ? 0.0f : g_w2[k*31 + (c-1)];
    }
    if (t < HID) { s_b1[t] = g_b1[t]; s_g[t] = g_lng[t]; s_lb[t] = g_lnb[t]; }
    if (t < 32)  {
        s_b2s[t] = (t == 0) ? 0.0f : g_b2[t-1];
        s_off[t] = (t < nbatch) ? g_off[t] : 0x7fffffff;
    }
    __syncthreads();

    const int s = t >> 2;
    const int p = t & 3;
    const int ntiles = (nobs + 63) >> 6;

    for (int tile = blockIdx.x; tile < ntiles; tile += gridDim.x) {
        const int base = tile << 6;
        for (int j = t; j < 64*28; j += 256) {
            int sl = j / 28, c = j - sl*28;
            float v = ((base + sl) < nobs) ? g_meta[(size_t)base*28 + j] : 0.f;
            s_X[sl*34 + 1 + c] = v;
        }
        if (t < 64) {
            const int gi = base + t;
            float o = 0.f; int ot = 0;
            if (gi < nobs) { o = g_obs[gi]; ot = g_otype[gi]; }
            s_X[t*34 + 0] = o;
            float4 e = ((const float4*)g_embed)[ot];
            s_X[t*34 + 29] = e.x; s_X[t*34 + 30] = e.y;
            s_X[t*34 + 31] = e.z; s_X[t*34 + 32] = e.w;
        }
        __syncthreads();

        float4 h0 = ((const float4*)s_b1)[p*4+0];
        float4 h1 = ((const float4*)s_b1)[p*4+1];
        float4 h2 = ((const float4*)s_b1)[p*4+2];
        float4 h3 = ((const float4*)s_b1)[p*4+3];
        const float* xrow = &s_X[s*34];
        #pragma unroll 2
        for (int k = 0; k < MLP_IN; ++k) {
            const float xk = xrow[k];
            const float4* wr = (const float4*)&s_w1[k*64 + p*16];
            float4 wa = wr[0], wb = wr[1], wc = wr[2], wd = wr[3];
            fma4(h0, xk, wa); fma4(h1, xk, wb);
            fma4(h2, xk, wc); fma4(h3, xk, wd);
        }
        float mu = (h0.x+h0.y+h0.z+h0.w) + (h1.x+h1.y+h1.z+h1.w)
                 + (h2.x+h2.y+h2.z+h2.w) + (h3.x+h3.y+h3.z+h3.w);
        mu += __shfl_xor(mu, 1, 64);
        mu += __shfl_xor(mu, 2, 64);
        mu *= (1.f/64.f);
        float var =
            (h0.x-mu)*(h0.x-mu)+(h0.y-mu)*(h0.y-mu)+(h0.z-mu)*(h0.z-mu)+(h0.w-mu)*(h0.w-mu)
          + (h1.x-mu)*(h1.x-mu)+(h1.y-mu)*(h1.y-mu)+(h1.z-mu)*(h1.z-mu)+(h1.w-mu)*(h1.w-mu)
          + (h2.x-mu)*(h2.x-mu)+(h2.y-mu)*(h2.y-mu)+(h2.z-mu)*(h2.z-mu)+(h2.w-mu)*(h2.w-mu)
          + (h3.x-mu)*(h3.x-mu)+(h3.y-mu)*(h3.y-mu)+(h3.z-mu)*(h3.z-mu)+(h3.w-mu)*(h3.w-mu);
        var += __shfl_xor(var, 1, 64);
        var += __shfl_xor(var, 2, 64);
        var *= (1.f/64.f);
        const float rs = rsqrtf(var + 1e-5f);
        const float4* g4 = (const float4*)&s_g[p*16];
        const float4* l4 = (const float4*)&s_lb[p*16];
        float4 ga = g4[0], gb = g4[1], gc = g4[2], gd = g4[3];
        float4 la = l4[0], lb_ = l4[1], lc = l4[2], ld = l4[3];
        #define LNSILU(hh, gg, ll) { \
            float v0 = (hh.x - mu) * rs * gg.x + ll.x; \
            float v1 = (hh.y - mu) * rs * gg.y + ll.y; \
            float v2 = (hh.z - mu) * rs * gg.z + ll.z; \
            float v3 = (hh.w - mu) * rs * gg.w + ll.w; \
            hh.x = v0 / (1.f + __expf(-v0)); \
            hh.y = v1 / (1.f + __expf(-v1)); \
            hh.z = v2 / (1.f + __expf(-v2)); \
            hh.w = v3 / (1.f + __expf(-v3)); }
        LNSILU(h0, ga, la); LNSILU(h1, gb, lb_);
        LNSILU(h2, gc, lc); LNSILU(h3, gd, ld);
        #undef LNSILU
        float4* hdst = (float4*)&s_H[s*68 + p*16];
        hdst[0] = h0; hdst[1] = h1; hdst[2] = h2; hdst[3] = h3;
        __syncthreads();

        float4 y0 = ((const float4*)s_b2s)[p*2+0];
        float4 y1 = ((const float4*)s_b2s)[p*2+1];
        const float* hrow = &s_H[s*68];
        #pragma unroll 2
        for (int k = 0; k < HID; ++k) {
            const float hk = hrow[k];
            const float4* wr = (const float4*)&s_w2s[k*32 + p*8];
            float4 wa = wr[0], wb = wr[1];
            fma4(y0, hk, wa); fma4(y1, hk, wb);
        }
        const int gi = base + s;
        if (gi < nobs) {
            int bidx = 0;
            for (int j2 = 0; j2 < nbatch; ++j2) bidx += (gi >= s_off[j2]) ? 1 : 0;
            if (bidx > nbatch - 1) bidx = nbatch - 1;
            const int seg = bidx * npix + g_pix[gi];
            const int bid = g_lplat[gi] * NCH_CONST + g_lch[gi];
            const float4* bkt = (const float4*)g_bucket + bid*8;
            float4 ba = bkt[p*2], bb = bkt[p*2+1];
            if (p == 0) y0.x = s_X[s*34];
            float* sp = g_sums + (size_t)seg * SED + p*8;
            atomAddF(&sp[0], y0.x+ba.x); atomAddF(&sp[1], y0.y+ba.y);
            atomAddF(&sp[2], y0.z+ba.z); atomAddF(&sp[3], y0.w+ba.w);
            atomAddF(&sp[4], y1.x+bb.x); atomAddF(&sp[5], y1.y+bb.y);
            atomAddF(&sp[6], y1.z+bb.z); atomAddF(&sp[7], y1.w+bb.w);
            if (p == 0) atomAddF(&g_cnts[seg], 1.0f);
        }
        __syncthreads();
    }
}

__global__ __launch_bounds__(256) void proj_meancnt_kernel(
    const float* __restrict__ g_sums, const float* __restrict__ g_cnts,
    const float* __restrict__ g_infill, const float* __restrict__ g_wp,
    const float* __restrict__ g_bp, float* __restrict__ g_out, int nseg)
{
    __shared__ __align__(16) float s_wp[SED*256];
    __shared__ __align__(16) float s_cell[CG][SED];
    const int t = threadIdx.x;
    const int half = blockIdx.y;
    const int cell0 = blockIdx.x * CG;
    for (int i = t; i < SED*64; i += 256) {
        int k = i >> 6, c4 = i & 63;
        ((float4*)s_wp)[k*64 + c4] = ((const float4*)g_wp)[k*128 + half*64 + c4];
    }
    for (int i = t; i < CG*SED; i += 256) {
        int g = i >> 5, c = i & 31;
        float cnt = g_cnts[cell0 + g];
        float s   = g_sums[(size_t)(cell0 + g)*SED + c];
        s_cell[g][c] = (cnt > 0.f) ? (s / fmaxf(cnt, 1.f)) : g_infill[c];
    }
    __syncthreads();
    #pragma unroll
    for (int it = 0; it < 4; ++it) {
        int idx4 = it*256 + t;
        int g  = idx4 >> 6;
        int c4 = idx4 & 63;
        float4 acc = ((const float4*)g_bp)[half*64 + c4];
        #pragma unroll
        for (int k = 0; k < SED; ++k) {
            float cg = s_cell[g][k];
            float4 w = ((const float4*)s_wp)[k*64 + c4];
            acc.x += cg*w.x; acc.y += cg*w.y; acc.z += cg*w.z; acc.w += cg*w.w;
        }
        ((float4*)g_out)[(size_t)(cell0 + g)*128 + half*64 + c4] = acc;
    }
}

// ===========================================================================
extern "C" void kernel_launch(void* const* d_in, const int* in_sizes, int n_in,
                              void* d_out, int out_size, void* d_ws, size_t ws_size,
                              hipStream_t stream)
{
    const float* obs    = (const float*)d_in[0];
    const float* meta   = (const float*)d_in[1];
    const int*   pix    = (const int*)d_in[2];
    const int*   lch    = (const int*)d_in[3];
    const int*   lplat  = (const int*)d_in[4];
    const int*   otype  = (const int*)d_in[5];
    const int*   offs   = (const int*)d_in[6];
    const float* embed  = (const float*)d_in[8];
    const float* w1     = (const float*)d_in[9];
    const float* b1     = (const float*)d_in[10];
    const float* lng    = (const float*)d_in[11];
    const float* lnb    = (const float*)d_in[12];
    const float* w2     = (const float*)d_in[13];
    const float* b2     = (const float*)d_in[14];
    const float* bucket = (const float*)d_in[15];
    const float* infill = (const float*)d_in[16];
    const float* wp     = (const float*)d_in[17];
    const float* bp     = (const float*)d_in[18];

    const int nobs   = in_sizes[0];
    const int nbatch = in_sizes[6];
    const int npix   = out_size / (nbatch * OUTD);
    const int nseg   = nbatch * npix;

    // ---- workspace layout (bytes) ----
    char* w = (char*)d_ws;
    size_t off = 0;
    int*   hist    = (int*)(w + off);   off += (size_t)nseg * 4;
    int*   base    = (int*)(w + off);   off += (size_t)nseg * 4;
    int*   cursor  = (int*)(w + off);   off += (size_t)nseg * 4;
    int*   btot    = (int*)(w + off);   off += 4096;
    float* enc     = (float*)(w + off); off += (size_t)nobs * SED * 4;
    const size_t need = off;

    const int ntiles     = (nobs + TILE3 - 1) / TILE3;
    const int gridMlp    = (ntiles < 2048) ? ntiles : 2048;
    const int blocksScan = (nseg + 511) / 512;   // must be <= 256

    if (ws_size >= need && blocksScan <= 256 && nseg <= (1 << 18)) {
        // ---- fast path: hist -> scan -> sorted-write MLP -> fused reduce+proj
        hipMemsetAsync(hist, 0, (size_t)nseg * 4, stream);

        seghist_kernel<<<(nobs + 255)/256, 256, 0, stream>>>(
            pix, offs, hist, nobs, npix, nbatch);

        scan_block_kernel<<<blocksScan, 256, 0, stream>>>(hist, base, btot, nseg);
        add_spine_kernel<<<(nseg + 255)/256, 256, 0, stream>>>(
            base, cursor, btot, blocksScan, nseg);

        mlp_encode_kernel<<<gridMlp, 256, 0, stream>>>(
            obs, meta, pix, lch, lplat, otype, offs,
            embed, w1, b1, lng, lnb, w2, b2, bucket,
            enc, cursor, nobs, npix, nbatch);

        reduce_proj_kernel<<<(nseg + CG - 1)/CG, 256, 0, stream>>>(
            enc, base, hist, infill, wp, bp, (float*)d_out, nseg);
    } else {
        // ---------------- fallback: atomic path ----------------
        float* sums = (float*)d_ws;
        float* cnts = sums + (size_t)nseg * SED;
        hipMemsetAsync(d_ws, 0, (size_t)nseg * (SED + 1) * sizeof(float), stream);
        const int ntiles64 = (nobs + 63) / 64;
        const int gridTok  = (ntiles64 < 2048) ? ntiles64 : 2048;
        tok_scatter_kernel<<<gridTok, 256, 0, stream>>>(
            obs, meta, pix, lch, lplat, otype, offs,
            embed, w1, b1, lng, lnb, w2, b2, bucket,
            sums, cnts, nobs, npix, nbatch);
        dim3 gp((nseg + CG - 1)/CG, 2, 1);
        proj_meancnt_kernel<<<gp, 256, 0, stream>>>(sums, cnts, infill, wp, bp,
                                                    (float*)d_out, nseg);
    }
}

// Round 13
// 624.920 us; speedup vs baseline: 1.1667x; 1.0384x over previous
//
#include <hip/hip_runtime.h>
#include <cstdint>
#include <cstddef>

// Problem constants
#define NCH_CONST 16     // bucket = platform*16 + channel
#define SED 32           // encoded feature dim
#define HID 64           // tokenizer hidden dim
#define MLP_IN 33        // 1 + 28 meta + 4 emb
#define OUTD 512         // projection output dim

#define TILE3 192        // 3 slots per quad: rows s, s+64, s+128

__device__ __forceinline__ void fma4(float4& acc, float xk, float4 wv) {
    acc.x = fmaf(xk, wv.x, acc.x);
    acc.y = fmaf(xk, wv.y, acc.y);
    acc.z = fmaf(xk, wv.z, acc.z);
    acc.w = fmaf(xk, wv.w, acc.w);
}

__device__ __forceinline__ void atomAddF(float* p, float v) {
    unsafeAtomicAdd(p, v);   // native global_atomic_add_f32 (fallback path only)
}

// ===========================================================================
// K0: seg histogram pre-pass.
// ===========================================================================
__global__ __launch_bounds__(256) void seghist_kernel(
    const int* __restrict__ g_pix, const int* __restrict__ g_off,
    int* __restrict__ g_hist, int nobs, int npix, int nbatch)
{
    __shared__ int s_off[32];
    if (threadIdx.x < 32)
        s_off[threadIdx.x] = (threadIdx.x < nbatch) ? g_off[threadIdx.x] : 0x7fffffff;
    __syncthreads();
    const int i = blockIdx.x * 256 + threadIdx.x;
    if (i < nobs) {
        int bidx = 0;
        for (int j = 0; j < nbatch; ++j) bidx += (i >= s_off[j]) ? 1 : 0;
        if (bidx > nbatch - 1) bidx = nbatch - 1;
        atomicAdd(&g_hist[bidx * npix + g_pix[i]], 1);
    }
}

// ===========================================================================
// K1 (R24): R20/R23 structure (proven 416 us) with ONE change: SiLU's IEEE
// float divide (v_div_scale/fmas/fixup ~8 instrs, 48 per thread-tile ~10%
// of VALU issue) replaced by v_rcp_f32, and LN rsqrt by v_rsq_f32. Error
// ~1 ulp, 4 orders below the 1/256 absmax tolerance. Everything else
// byte-identical: 3 slots/quad, barrier-free per-wave ownership, issue-
// early/write-late staging, weights in LDS, packed segbid.
// ===========================================================================

#define P2S3(xa, xb, xc, K) {                                                  \
    const float4* wr = (const float4*)&s_w1p[(K)*64 + p*16];                   \
    float4 wa = wr[0], wb = wr[1], wc = wr[2], wd = wr[3];                     \
    fma4(hA0, (xa), wa); fma4(hA1, (xa), wb);                                  \
    fma4(hA2, (xa), wc); fma4(hA3, (xa), wd);                                  \
    fma4(hB0, (xb), wa); fma4(hB1, (xb), wb);                                  \
    fma4(hB2, (xb), wc); fma4(hB3, (xb), wd);                                  \
    fma4(hC0, (xc), wa); fma4(hC1, (xc), wb);                                  \
    fma4(hC2, (xc), wc); fma4(hC3, (xc), wd); }

#define P3S3(ha, hb, hc, K) {                                                  \
    const float4* wr = (const float4*)&s_w2s[(K)*32 + p*8];                    \
    float4 wa = wr[0], wb = wr[1];                                             \
    fma4(yA0, (ha), wa); fma4(yA1, (ha), wb);                                  \
    fma4(yB0, (hb), wa); fma4(yB1, (hb), wb);                                  \
    fma4(yC0, (hc), wa); fma4(yC1, (hc), wb); }

#define STG_LOAD(TT) {                                                         \
    const int mA = (((TT) * TILE3) + rowA0) * 28;                              \
    _Pragma("unroll")                                                          \
    for (int g = 0; g < 3; ++g) {                                              \
        const int mb = mA + g * (64*28);                                       \
        _Pragma("unroll")                                                      \
        for (int i = 0; i < 7; ++i) {                                          \
            const int j = mb + lane + (i << 6);                                \
            pfm[g][i] = (j < nmeta) ? g_meta[j] : 0.f;                         \
        }                                                                      \
    }                                                                          \
    if (lane < 48) {                                                           \
        const int rr = rowA0 + ((lane >> 4) << 6) + (lane & 15);               \
        const int gi = (TT) * TILE3 + rr;                                      \
        const bool v = gi < nobs;                                              \
        pf_o = v ? g_obs[gi] : 0.f;                                            \
        const int ot = v ? g_otype[gi] : 0;                                    \
        pf_e = ((const float4*)g_embed)[ot];                                   \
        const int px = v ? g_pix[gi] : 0;                                      \
        const int pl = v ? g_lplat[gi] : 0;                                    \
        const int lc = v ? g_lch[gi] : 0;                                      \
        int bidx = 0;                                                          \
        for (int j2 = 0; j2 < nbatch; ++j2) bidx += (gi >= s_off[j2]) ? 1 : 0; \
        if (bidx > nbatch - 1) bidx = nbatch - 1;                              \
        pf_seg = bidx * npix + px;                                             \
        pf_bid = pl * NCH_CONST + lc;                                          \
        pf_rr = rr;                                                            \
    }                                                                          \
}

#define STG_WRITE() {                                                          \
    _Pragma("unroll")                                                          \
    for (int g = 0; g < 3; ++g) {                                              \
        const int rb = rowA0 + (g << 6);                                       \
        _Pragma("unroll")                                                      \
        for (int i = 0; i < 7; ++i) {                                          \
            const int ii = lane + (i << 6);                                    \
            const int sl = ii / 28, cc = ii - sl * 28;                         \
            s_XH[(rb + sl) * 68 + cc] = pfm[g][i];                             \
        }                                                                      \
    }                                                                          \
    if (lane < 48) {                                                           \
        s_XH[pf_rr * 68 + 32] = pf_o;                                          \
        *(float4*)&s_XH[pf_rr * 68 + 28] = pf_e;                               \
        s_segbid[pf_rr] = pf_seg | (pf_bid << 18);                             \
    }                                                                          \
}

__global__ __launch_bounds__(256, 2) void mlp_encode_kernel(
    const float* __restrict__ g_obs,
    const float* __restrict__ g_meta,
    const int*   __restrict__ g_pix,
    const int*   __restrict__ g_lch,
    const int*   __restrict__ g_lplat,
    const int*   __restrict__ g_otype,
    const int*   __restrict__ g_off,
    const float* __restrict__ g_embed,
    const float* __restrict__ g_w1,
    const float* __restrict__ g_b1,
    const float* __restrict__ g_lng,
    const float* __restrict__ g_lnb,
    const float* __restrict__ g_w2,
    const float* __restrict__ g_b2,
    const float* __restrict__ g_bucket,
    float* __restrict__ g_enc,      // (nobs, 32) SORTED-position encoded rows
    int*   __restrict__ g_cursor,   // (nseg,) = base after scan; bumped here
    int nobs, int npix, int nbatch)
{
    __shared__ __align__(16) float s_w1p[MLP_IN*HID]; // 8448 B, PERMUTED rows
    __shared__ __align__(16) float s_w2s[HID*32];     // shifted, 8192 B
    __shared__ __align__(16) float s_b1[HID];
    __shared__ __align__(16) float s_g[HID];
    __shared__ __align__(16) float s_lb[HID];
    __shared__ __align__(16) float s_b2s[32];         // shifted b2 (c0 = 0)
    __shared__ int   s_off[32];
    __shared__ int   s_segbid[TILE3];                 // seg | (bid<<18)
    __shared__ __align__(16) float s_XH[TILE3*68];    // X(33u)/H(64u) overlay

    const int t = threadIdx.x;

    for (int i = t; i < MLP_IN*HID; i += 256) {
        const int c = i >> 6, j = i & 63;
        const int kp = (c == 32) ? 0 : (c + 1);  // meta c->w1 row c+1; obs(32)->row 0
        s_w1p[i] = g_w1[kp*64 + j];
    }
    for (int i = t; i < HID*32; i += 256) {
        int k = i >> 5, c = i & 31;
        s_w2s[i] = (c == 0) ? 0.0f : g_w2[k*31 + (c-1)];
    }
    if (t < HID) { s_b1[t] = g_b1[t]; s_g[t] = g_lng[t]; s_lb[t] = g_lnb[t]; }
    if (t < 32)  {
        s_b2s[t] = (t == 0) ? 0.0f : g_b2[t-1];
        s_off[t] = (t < nbatch) ? g_off[t] : 0x7fffffff;
    }
    __syncthreads();   // the ONLY barrier

    const int w = t >> 6;        // wave id (0..3)
    const int lane = t & 63;
    const int s = t >> 2;        // slot group; wave w owns s in [16w,16w+16)
    const int p = t & 3;         // part (h[16p..16p+15], enc ch [8p,8p+8))
    const int rowA0 = w << 4;
    const int ntiles = (nobs + TILE3 - 1) / TILE3;
    const int stride = gridDim.x;
    const int nmeta = nobs * 28;

    float pfm[3][7];
    float pf_o = 0.f;
    float4 pf_e = make_float4(0.f, 0.f, 0.f, 0.f);
    int pf_seg = 0, pf_bid = 0, pf_rr = 0;

    int tile = blockIdx.x;
    if (tile < ntiles) {
        STG_LOAD(tile)
        STG_WRITE()
    }

    for (; tile < ntiles; tile += stride) {
        const int nt = tile + stride;
        const bool has_next = nt < ntiles;
        if (has_next) STG_LOAD(nt)

        const int base = tile * TILE3;

        float4 hA0 = ((const float4*)s_b1)[p*4+0];
        float4 hA1 = ((const float4*)s_b1)[p*4+1];
        float4 hA2 = ((const float4*)s_b1)[p*4+2];
        float4 hA3 = ((const float4*)s_b1)[p*4+3];
        float4 hB0 = hA0, hB1 = hA1, hB2 = hA2, hB3 = hA3;
        float4 hC0 = hA0, hC1 = hA1, hC2 = hA2, hC3 = hA3;
        const float* xrowA = &s_XH[s*68];
        const float* xrowB = &s_XH[(s+64)*68];
        const float* xrowC = &s_XH[(s+128)*68];
        const float oA = xrowA[32];
        const float oB = xrowB[32];
        const float oC = xrowC[32];
        #pragma unroll 4
        for (int k4 = 0; k4 < 8; ++k4) {
            const float4 xvA = ((const float4*)xrowA)[k4];
            const float4 xvB = ((const float4*)xrowB)[k4];
            const float4 xvC = ((const float4*)xrowC)[k4];
            const int kb = k4 * 4;
            P2S3(xvA.x, xvB.x, xvC.x, kb+0)
            P2S3(xvA.y, xvB.y, xvC.y, kb+1)
            P2S3(xvA.z, xvB.z, xvC.z, kb+2)
            P2S3(xvA.w, xvB.w, xvC.w, kb+3)
        }
        P2S3(oA, oB, oC, 32)

        #define HS4(h0,h1,h2,h3) ((h0.x+h0.y+h0.z+h0.w)+(h1.x+h1.y+h1.z+h1.w)+ \
                                  (h2.x+h2.y+h2.z+h2.w)+(h3.x+h3.y+h3.z+h3.w))
        float muA = HS4(hA0,hA1,hA2,hA3);
        float muB = HS4(hB0,hB1,hB2,hB3);
        float muC = HS4(hC0,hC1,hC2,hC3);
        #undef HS4
        muA += __shfl_xor(muA, 1, 64); muB += __shfl_xor(muB, 1, 64);
        muC += __shfl_xor(muC, 1, 64);
        muA += __shfl_xor(muA, 2, 64); muB += __shfl_xor(muB, 2, 64);
        muC += __shfl_xor(muC, 2, 64);
        muA *= (1.f/64.f); muB *= (1.f/64.f); muC *= (1.f/64.f);
        #define SQS(hh, mm) ((hh.x-mm)*(hh.x-mm)+(hh.y-mm)*(hh.y-mm)+ \
                             (hh.z-mm)*(hh.z-mm)+(hh.w-mm)*(hh.w-mm))
        float varA = SQS(hA0,muA) + SQS(hA1,muA) + SQS(hA2,muA) + SQS(hA3,muA);
        float varB = SQS(hB0,muB) + SQS(hB1,muB) + SQS(hB2,muB) + SQS(hB3,muB);
        float varC = SQS(hC0,muC) + SQS(hC1,muC) + SQS(hC2,muC) + SQS(hC3,muC);
        #undef SQS
        varA += __shfl_xor(varA, 1, 64); varB += __shfl_xor(varB, 1, 64);
        varC += __shfl_xor(varC, 1, 64);
        varA += __shfl_xor(varA, 2, 64); varB += __shfl_xor(varB, 2, 64);
        varC += __shfl_xor(varC, 2, 64);
        const float rsA = __builtin_amdgcn_rsqf(varA*(1.f/64.f) + 1e-5f);
        const float rsB = __builtin_amdgcn_rsqf(varB*(1.f/64.f) + 1e-5f);
        const float rsC = __builtin_amdgcn_rsqf(varC*(1.f/64.f) + 1e-5f);

        const float4* g4 = (const float4*)&s_g[p*16];
        const float4* l4 = (const float4*)&s_lb[p*16];
        float4 ga = g4[0], gb = g4[1], gc = g4[2], gd = g4[3];
        float4 la = l4[0], lb_ = l4[1], lc = l4[2], ld = l4[3];
        // SiLU via v_rcp_f32 (1 instr) instead of IEEE divide (~8 instrs);
        // ~1 ulp error << 1/256 absmax tolerance.
        #define LNSILU(hh, mm, rr, gg, ll) { \
            float v0 = (hh.x - mm) * rr * gg.x + ll.x; \
            float v1 = (hh.y - mm) * rr * gg.y + ll.y; \
            float v2 = (hh.z - mm) * rr * gg.z + ll.z; \
            float v3 = (hh.w - mm) * rr * gg.w + ll.w; \
            hh.x = v0 * __builtin_amdgcn_rcpf(1.f + __expf(-v0)); \
            hh.y = v1 * __builtin_amdgcn_rcpf(1.f + __expf(-v1)); \
            hh.z = v2 * __builtin_amdgcn_rcpf(1.f + __expf(-v2)); \
            hh.w = v3 * __builtin_amdgcn_rcpf(1.f + __expf(-v3)); }
        LNSILU(hA0, muA, rsA, ga, la); LNSILU(hA1, muA, rsA, gb, lb_);
        LNSILU(hA2, muA, rsA, gc, lc); LNSILU(hA3, muA, rsA, gd, ld);
        LNSILU(hB0, muB, rsB, ga, la); LNSILU(hB1, muB, rsB, gb, lb_);
        LNSILU(hB2, muB, rsB, gc, lc); LNSILU(hB3, muB, rsB, gd, ld);
        LNSILU(hC0, muC, rsC, ga, la); LNSILU(hC1, muC, rsC, gb, lb_);
        LNSILU(hC2, muC, rsC, gc, lc); LNSILU(hC3, muC, rsC, gd, ld);
        #undef LNSILU

        float4* hdstA = (float4*)&s_XH[s*68 + p*16];
        hdstA[0] = hA0; hdstA[1] = hA1; hdstA[2] = hA2; hdstA[3] = hA3;
        float4* hdstB = (float4*)&s_XH[(s+64)*68 + p*16];
        hdstB[0] = hB0; hdstB[1] = hB1; hdstB[2] = hB2; hdstB[3] = hB3;
        float4* hdstC = (float4*)&s_XH[(s+128)*68 + p*16];
        hdstC[0] = hC0; hdstC[1] = hC1; hdstC[2] = hC2; hdstC[3] = hC3;

        float4 yA0 = ((const float4*)s_b2s)[p*2+0];
        float4 yA1 = ((const float4*)s_b2s)[p*2+1];
        float4 yB0 = yA0, yB1 = yA1;
        float4 yC0 = yA0, yC1 = yA1;
        const float* hrowA = &s_XH[s*68];
        const float* hrowB = &s_XH[(s+64)*68];
        const float* hrowC = &s_XH[(s+128)*68];
        #pragma unroll 4
        for (int k4 = 0; k4 < 16; ++k4) {
            const float4 hvA = ((const float4*)hrowA)[k4];
            const float4 hvB = ((const float4*)hrowB)[k4];
            const float4 hvC = ((const float4*)hrowC)[k4];
            const int kb = k4 * 4;
            P3S3(hvA.x, hvB.x, hvC.x, kb+0)
            P3S3(hvA.y, hvB.y, hvC.y, kb+1)
            P3S3(hvA.z, hvB.z, hvC.z, kb+2)
            P3S3(hvA.w, hvB.w, hvC.w, kb+3)
        }

        const int giA = base + s;
        const int giB = giA + 64;
        const int giC = giA + 128;
        int posA = 0, posB = 0, posC = 0;
        if (p == 0) {
            if (giA < nobs) posA = atomicAdd(&g_cursor[s_segbid[s] & 0x3FFFF], 1);
            if (giB < nobs) posB = atomicAdd(&g_cursor[s_segbid[s+64] & 0x3FFFF], 1);
            if (giC < nobs) posC = atomicAdd(&g_cursor[s_segbid[s+128] & 0x3FFFF], 1);
        }
        posA = __shfl(posA, lane & ~3, 64);
        posB = __shfl(posB, lane & ~3, 64);
        posC = __shfl(posC, lane & ~3, 64);

        if (giA < nobs) {
            const float4* bkt = (const float4*)g_bucket + (s_segbid[s] >> 18)*8;
            float4 ba = bkt[p*2], bb = bkt[p*2+1];
            if (p == 0) yA0.x = oA;
            float4 r0 = make_float4(yA0.x+ba.x, yA0.y+ba.y, yA0.z+ba.z, yA0.w+ba.w);
            float4 r1 = make_float4(yA1.x+bb.x, yA1.y+bb.y, yA1.z+bb.z, yA1.w+bb.w);
            float4* dst = (float4*)(g_enc + (size_t)posA * SED + p*8);
            dst[0] = r0; dst[1] = r1;
        }
        if (giB < nobs) {
            const float4* bkt = (const float4*)g_bucket + (s_segbid[s+64] >> 18)*8;
            float4 ba = bkt[p*2], bb = bkt[p*2+1];
            if (p == 0) yB0.x = oB;
            float4 r0 = make_float4(yB0.x+ba.x, yB0.y+ba.y, yB0.z+ba.z, yB0.w+ba.w);
            float4 r1 = make_float4(yB1.x+bb.x, yB1.y+bb.y, yB1.z+bb.z, yB1.w+bb.w);
            float4* dst = (float4*)(g_enc + (size_t)posB * SED + p*8);
            dst[0] = r0; dst[1] = r1;
        }
        if (giC < nobs) {
            const float4* bkt = (const float4*)g_bucket + (s_segbid[s+128] >> 18)*8;
            float4 ba = bkt[p*2], bb = bkt[p*2+1];
            if (p == 0) yC0.x = oC;
            float4 r0 = make_float4(yC0.x+ba.x, yC0.y+ba.y, yC0.z+ba.z, yC0.w+ba.w);
            float4 r1 = make_float4(yC1.x+bb.x, yC1.y+bb.y, yC1.z+bb.z, yC1.w+bb.w);
            float4* dst = (float4*)(g_enc + (size_t)posC * SED + p*8);
            dst[0] = r0; dst[1] = r1;
        }

        if (has_next) STG_WRITE()
    }
}

// ---------------------------------------------------------------------------
// K2a: per-block exclusive scan of hist (512 elems/block), RAW block totals
// ---------------------------------------------------------------------------
__global__ __launch_bounds__(256) void scan_block_kernel(
    const int* __restrict__ g_hist, int* __restrict__ g_base,
    int* __restrict__ g_btot, int n)
{
    __shared__ int s[512];
    const int t  = threadIdx.x;
    const int i0 = blockIdx.x * 512 + t;
    const int i1 = i0 + 256;
    const int o0 = (i0 < n) ? g_hist[i0] : 0;
    const int o1 = (i1 < n) ? g_hist[i1] : 0;
    s[t] = o0; s[t+256] = o1;
    __syncthreads();
    for (int off = 1; off < 512; off <<= 1) {
        int a = (t >= off) ? s[t - off] : 0;
        int b = s[t + 256 - off];
        __syncthreads();
        s[t] += a; s[t+256] += b;
        __syncthreads();
    }
    if (i0 < n) g_base[i0] = s[t] - o0;
    if (i1 < n) g_base[i1] = s[t+256] - o1;
    if (t == 255) g_btot[blockIdx.x] = s[511];
}

// ---------------------------------------------------------------------------
// K2b: add_spine with INLINE spine prefix (kills scan_spine launch).
// ---------------------------------------------------------------------------
__global__ __launch_bounds__(256) void add_spine_kernel(
    int* __restrict__ g_base, int* __restrict__ g_cursor,
    const int* __restrict__ g_btot, int nblocksScan, int n)
{
    __shared__ int s[256];
    const int t = threadIdx.x;
    const int sb = blockIdx.x >> 1;       // scan-block covering this add-block
    s[t] = (t < sb && t < nblocksScan) ? g_btot[t] : 0;
    __syncthreads();
    for (int off = 128; off > 0; off >>= 1) {
        if (t < off) s[t] += s[t + off];
        __syncthreads();
    }
    const int prefix = s[0];
    const int i = blockIdx.x * 256 + t;
    if (i < n) {
        int v = g_base[i] + prefix;
        g_base[i] = v;
        g_cursor[i] = v;
    }
}

// ---------------------------------------------------------------------------
// K4+K5 fused (R21 proj, PROVEN — R22's transposed variant regressed +81 us;
// compiler LICM already hoists the it-invariant w reads): reduce 16 segments
// -> s_cell (threads 0-127) while threads 128-255 stage wp into LDS; then
// all 256 threads project the 16x512 output tile.
// ---------------------------------------------------------------------------
#define CG 16
__device__ __forceinline__ void add4(float4& a, float4 b) {
    a.x += b.x; a.y += b.y; a.z += b.z; a.w += b.w;
}

__global__ __launch_bounds__(256) void reduce_proj_kernel(
    const float* __restrict__ g_enc,
    const int*   __restrict__ g_base,
    const int*   __restrict__ g_hist,
    const float* __restrict__ g_infill,
    const float* __restrict__ g_wp,
    const float* __restrict__ g_bp,
    float* __restrict__ g_out,
    int nseg)
{
    __shared__ __align__(16) float s_wp[SED*OUTD];    // 65536 B
    __shared__ __align__(16) float s_cell[CG][SED];   // 2048 B

    const int t = threadIdx.x;
    const int cell0 = blockIdx.x * CG;

    if (t < 128) {
        // ---- reduce phase: 16 segs x 8 lanes ----
        const int gl = t >> 3;            // local segment 0..15
        const int c4 = t & 7;             // float4 column
        const int g  = cell0 + gl;
        float4 r = make_float4(0,0,0,0);
        if (g < nseg) {
            const int b = g_base[g];
            const int n = g_hist[g];
            const float4* src = (const float4*)g_enc + (size_t)b * 8 + c4;
            float4 a0 = make_float4(0,0,0,0), a1 = a0, a2 = a0, a3 = a0;
            int j = 0;
            for (; j + 3 < n; j += 4) {
                float4 v0 = src[(size_t)(j+0)*8];
                float4 v1 = src[(size_t)(j+1)*8];
                float4 v2 = src[(size_t)(j+2)*8];
                float4 v3 = src[(size_t)(j+3)*8];
                add4(a0, v0); add4(a1, v1); add4(a2, v2); add4(a3, v3);
            }
            for (; j < n; ++j) add4(a0, src[(size_t)j*8]);
            add4(a0, a1); add4(a2, a3); add4(a0, a2);
            if (n > 0) {
                const float inv = 1.f / (float)n;
                r = make_float4(a0.x*inv, a0.y*inv, a0.z*inv, a0.w*inv);
            } else {
                r = ((const float4*)g_infill)[c4];
            }
        }
        *(float4*)&s_cell[gl][c4*4] = r;
    } else {
        // ---- wp staging phase: 128 threads copy 4096 float4 (64 KB) ----
        const int t2 = t - 128;
        #pragma unroll
        for (int i = 0; i < 32; ++i) {
            const int idx = t2 + i*128;
            ((float4*)s_wp)[idx] = ((const float4*)g_wp)[idx];
        }
    }
    __syncthreads();

    // ---- proj phase: 16 cells x 128 float4 cols = 2048 float4; 8/thread ----
    #pragma unroll
    for (int it = 0; it < 8; ++it) {
        const int idx4 = it*256 + t;
        const int g  = idx4 >> 7;         // 0..15
        const int c4 = idx4 & 127;        // 0..127
        if (cell0 + g < nseg) {
            float4 acc = ((const float4*)g_bp)[c4];
            #pragma unroll
            for (int k = 0; k < SED; ++k) {
                const float cg = s_cell[g][k];
                const float4 w = ((const float4*)s_wp)[k*128 + c4];
                acc.x += cg*w.x; acc.y += cg*w.y; acc.z += cg*w.z; acc.w += cg*w.w;
            }
            ((float4*)g_out)[(size_t)(cell0 + g)*128 + c4] = acc;
        }
    }
}

// ===========================================================================
// FALLBACK (ws too small or nseg too large for packed segbid): atomic path
// ===========================================================================
__global__ __launch_bounds__(256, 2) void tok_scatter_kernel(
    const float* __restrict__ g_obs, const float* __restrict__ g_meta,
    const int* __restrict__ g_pix, const int* __restrict__ g_lch,
    const int* __restrict__ g_lplat, const int* __restrict__ g_otype,
    const int* __restrict__ g_off, const float* __restrict__ g_embed,
    const float* __restrict__ g_w1, const float* __restrict__ g_b1,
    const float* __restrict__ g_lng, const float* __restrict__ g_lnb,
    const float* __restrict__ g_w2, const float* __restrict__ g_b2,
    const float* __restrict__ g_bucket,
    float* __restrict__ g_sums, float* __restrict__ g_cnts,
    int nobs, int npix, int nbatch)
{
    __shared__ __align__(16) float s_w1[MLP_IN*HID];
    __shared__ __align__(16) float s_w2s[HID*32];
    __shared__ __align__(16) float s_b1[HID], s_g[HID], s_lb[HID];
    __shared__ __align__(16) float s_b2s[32];
    __shared__ int   s_off[32];
    __shared__ __align__(16) float s_X[64*34];
    __shared__ __align__(16) float s_H[64*68];

    const int t = threadIdx.x;
    for (int i = t; i < MLP_IN*HID; i += 256) s_w1[i] = g_w1[i];
    for (int i = t; i < HID*32; i += 256) {
        int k = i >> 5, c = i & 31;
        s_w2s[i] = (c == 0) ? 0.0f : g_w2[k*31 + (c-1)];
    }
    if (t < HID) { s_b1[t] = g_b1[t]; s_g[t] = g_lng[t]; s_lb[t] = g_lnb[t]; }
    if (t < 32)  {
        s_b2s[t] = (t == 0) ? 0.0f : g_b2[t-1];
        s_off[t] = (t < nbatch) ? g_off[t] : 0x7fffffff;
    }
    __syncthreads();

    const int s = t >> 2;
    const int p = t & 3;
    const int ntiles = (nobs + 63) >> 6;

    for (int tile = blockIdx.x; tile < ntiles; tile += gridDim.x) {
        const int base = tile << 6;
        for (int j = t; j < 64*28; j += 256) {
            int sl = j / 28, c = j - sl*28;
            float v = ((base + sl) < nobs) ? g_meta[(size_t)base*28 + j] : 0.f;
            s_X[sl*34 + 1 + c] = v;
        }
        if (t < 64) {
            const int gi = base + t;
            float o = 0.f; int ot = 0;
            if (gi < nobs) { o = g_obs[gi]; ot = g_otype[gi]; }
            s_X[t*34 + 0] = o;
            float4 e = ((const float4*)g_embed)[ot];
            s_X[t*34 + 29] = e.x; s_X[t*34 + 30] = e.y;
            s_X[t*34 + 31] = e.z; s_X[t*34 + 32] = e.w;
        }
        __syncthreads();

        float4 h0 = ((const float4*)s_b1)[p*4+0];
        float4 h1 = ((const float4*)s_b1)[p*4+1];
        float4 h2 = ((const float4*)s_b1)[p*4+2];
        float4 h3 = ((const float4*)s_b1)[p*4+3];
        const float* xrow = &s_X[s*34];
        #pragma unroll 2
        for (int k = 0; k < MLP_IN; ++k) {
            const float xk = xrow[k];
            const float4* wr = (const float4*)&s_w1[k*64 + p*16];
            float4 wa = wr[0], wb = wr[1], wc = wr[2], wd = wr[3];
            fma4(h0, xk, wa); fma4(h1, xk, wb);
            fma4(h2, xk, wc); fma4(h3, xk, wd);
        }
        float mu = (h0.x+h0.y+h0.z+h0.w) + (h1.x+h1.y+h1.z+h1.w)
                 + (h2.x+h2.y+h2.z+h2.w) + (h3.x+h3.y+h3.z+h3.w);
        mu += __shfl_xor(mu, 1, 64);
        mu += __shfl_xor(mu, 2, 64);
        mu *= (1.f/64.f);
        float var =
            (h0.x-mu)*(h0.x-mu)+(h0.y-mu)*(h0.y-mu)+(h0.z-mu)*(h0.z-mu)+(h0.w-mu)*(h0.w-mu)
          + (h1.x-mu)*(h1.x-mu)+(h1.y-mu)*(h1.y-mu)+(h1.z-mu)*(h1.z-mu)+(h1.w-mu)*(h1.w-mu)
          + (h2.x-mu)*(h2.x-mu)+(h2.y-mu)*(h2.y-mu)+(h2.z-mu)*(h2.z-mu)+(h2.w-mu)*(h2.w-mu)
          + (h3.x-mu)*(h3.x-mu)+(h3.y-mu)*(h3.y-mu)+(h3.z-mu)*(h3.z-mu)+(h3.w-mu)*(h3.w-mu);
        var += __shfl_xor(var, 1, 64);
        var += __shfl_xor(var, 2, 64);
        var *= (1.f/64.f);
        const float rs = rsqrtf(var + 1e-5f);
        const float4* g4 = (const float4*)&s_g[p*16];
        const float4* l4 = (const float4*)&s_lb[p*16];
        float4 ga = g4[0], gb = g4[1], gc = g4[2], gd = g4[3];
        float4 la = l4[0], lb_ = l4[1], lc = l4[2], ld = l4[3];
        #define LNSILU(hh, gg, ll) { \
            float v0 = (hh.x - mu) * rs * gg.x + ll.x; \
            float v1 = (hh.y - mu) * rs * gg.y + ll.y; \
            float v2 = (hh.z - mu) * rs * gg.z + ll.z; \
            float v3 = (hh.w - mu) * rs * gg.w + ll.w; \
            hh.x = v0 / (1.f + __expf(-v0)); \
            hh.y = v1 / (1.f + __expf(-v1)); \
            hh.z = v2 / (1.f + __expf(-v2)); \
            hh.w = v3 / (1.f + __expf(-v3)); }
        LNSILU(h0, ga, la); LNSILU(h1, gb, lb_);
        LNSILU(h2, gc, lc); LNSILU(h3, gd, ld);
        #undef LNSILU
        float4* hdst = (float4*)&s_H[s*68 + p*16];
        hdst[0] = h0; hdst[1] = h1; hdst[2] = h2; hdst[3] = h3;
        __syncthreads();

        float4 y0 = ((const float4*)s_b2s)[p*2+0];
        float4 y1 = ((const float4*)s_b2s)[p*2+1];
        const float* hrow = &s_H[s*68];
        #pragma unroll 2
        for (int k = 0; k < HID; ++k) {
            const float hk = hrow[k];
            const float4* wr = (const float4*)&s_w2s[k*32 + p*8];
            float4 wa = wr[0], wb = wr[1];
            fma4(y0, hk, wa); fma4(y1, hk, wb);
        }
        const int gi = base + s;
        if (gi < nobs) {
            int bidx = 0;
            for (int j2 = 0; j2 < nbatch; ++j2) bidx += (gi >= s_off[j2]) ? 1 : 0;
            if (bidx > nbatch - 1) bidx = nbatch - 1;
            const int seg = bidx * npix + g_pix[gi];
            const int bid = g_lplat[gi] * NCH_CONST + g_lch[gi];
            const float4* bkt = (const float4*)g_bucket + bid*8;
            float4 ba = bkt[p*2], bb = bkt[p*2+1];
            if (p == 0) y0.x = s_X[s*34];
            float* sp = g_sums + (size_t)seg * SED + p*8;
            atomAddF(&sp[0], y0.x+ba.x); atomAddF(&sp[1], y0.y+ba.y);
            atomAddF(&sp[2], y0.z+ba.z); atomAddF(&sp[3], y0.w+ba.w);
            atomAddF(&sp[4], y1.x+bb.x); atomAddF(&sp[5], y1.y+bb.y);
            atomAddF(&sp[6], y1.z+bb.z); atomAddF(&sp[7], y1.w+bb.w);
            if (p == 0) atomAddF(&g_cnts[seg], 1.0f);
        }
        __syncthreads();
    }
}

__global__ __launch_bounds__(256) void proj_meancnt_kernel(
    const float* __restrict__ g_sums, const float* __restrict__ g_cnts,
    const float* __restrict__ g_infill, const float* __restrict__ g_wp,
    const float* __restrict__ g_bp, float* __restrict__ g_out, int nseg)
{
    __shared__ __align__(16) float s_wp[SED*256];
    __shared__ __align__(16) float s_cell[CG][SED];
    const int t = threadIdx.x;
    const int half = blockIdx.y;
    const int cell0 = blockIdx.x * CG;
    for (int i = t; i < SED*64; i += 256) {
        int k = i >> 6, c4 = i & 63;
        ((float4*)s_wp)[k*64 + c4] = ((const float4*)g_wp)[k*128 + half*64 + c4];
    }
    for (int i = t; i < CG*SED; i += 256) {
        int g = i >> 5, c = i & 31;
        float cnt = g_cnts[cell0 + g];
        float s   = g_sums[(size_t)(cell0 + g)*SED + c];
        s_cell[g][c] = (cnt > 0.f) ? (s / fmaxf(cnt, 1.f)) : g_infill[c];
    }
    __syncthreads();
    #pragma unroll
    for (int it = 0; it < 4; ++it) {
        int idx4 = it*256 + t;
        int g  = idx4 >> 6;
        int c4 = idx4 & 63;
        float4 acc = ((const float4*)g_bp)[half*64 + c4];
        #pragma unroll
        for (int k = 0; k < SED; ++k) {
            float cg = s_cell[g][k];
            float4 w = ((const float4*)s_wp)[k*64 + c4];
            acc.x += cg*w.x; acc.y += cg*w.y; acc.z += cg*w.z; acc.w += cg*w.w;
        }
        ((float4*)g_out)[(size_t)(cell0 + g)*128 + half*64 + c4] = acc;
    }
}

// ===========================================================================
extern "C" void kernel_launch(void* const* d_in, const int* in_sizes, int n_in,
                              void* d_out, int out_size, void* d_ws, size_t ws_size,
                              hipStream_t stream)
{
    const float* obs    = (const float*)d_in[0];
    const float* meta   = (const float*)d_in[1];
    const int*   pix    = (const int*)d_in[2];
    const int*   lch    = (const int*)d_in[3];
    const int*   lplat  = (const int*)d_in[4];
    const int*   otype  = (const int*)d_in[5];
    const int*   offs   = (const int*)d_in[6];
    const float* embed  = (const float*)d_in[8];
    const float* w1     = (const float*)d_in[9];
    const float* b1     = (const float*)d_in[10];
    const float* lng    = (const float*)d_in[11];
    const float* lnb    = (const float*)d_in[12];
    const float* w2     = (const float*)d_in[13];
    const float* b2     = (const float*)d_in[14];
    const float* bucket = (const float*)d_in[15];
    const float* infill = (const float*)d_in[16];
    const float* wp     = (const float*)d_in[17];
    const float* bp     = (const float*)d_in[18];

    const int nobs   = in_sizes[0];
    const int nbatch = in_sizes[6];
    const int npix   = out_size / (nbatch * OUTD);
    const int nseg   = nbatch * npix;

    // ---- workspace layout (bytes) ----
    char* w = (char*)d_ws;
    size_t off = 0;
    int*   hist    = (int*)(w + off);   off += (size_t)nseg * 4;
    int*   base    = (int*)(w + off);   off += (size_t)nseg * 4;
    int*   cursor  = (int*)(w + off);   off += (size_t)nseg * 4;
    int*   btot    = (int*)(w + off);   off += 4096;
    float* enc     = (float*)(w + off); off += (size_t)nobs * SED * 4;
    const size_t need = off;

    const int ntiles     = (nobs + TILE3 - 1) / TILE3;
    const int gridMlp    = (ntiles < 2048) ? ntiles : 2048;
    const int blocksScan = (nseg + 511) / 512;   // must be <= 256

    if (ws_size >= need && blocksScan <= 256 && nseg <= (1 << 18)) {
        // ---- fast path: hist -> scan -> sorted-write MLP -> fused reduce+proj
        hipMemsetAsync(hist, 0, (size_t)nseg * 4, stream);

        seghist_kernel<<<(nobs + 255)/256, 256, 0, stream>>>(
            pix, offs, hist, nobs, npix, nbatch);

        scan_block_kernel<<<blocksScan, 256, 0, stream>>>(hist, base, btot, nseg);
        add_spine_kernel<<<(nseg + 255)/256, 256, 0, stream>>>(
            base, cursor, btot, blocksScan, nseg);

        mlp_encode_kernel<<<gridMlp, 256, 0, stream>>>(
            obs, meta, pix, lch, lplat, otype, offs,
            embed, w1, b1, lng, lnb, w2, b2, bucket,
            enc, cursor, nobs, npix, nbatch);

        reduce_proj_kernel<<<(nseg + CG - 1)/CG, 256, 0, stream>>>(
            enc, base, hist, infill, wp, bp, (float*)d_out, nseg);
    } else {
        // ---------------- fallback: atomic path ----------------
        float* sums = (float*)d_ws;
        float* cnts = sums + (size_t)nseg * SED;
        hipMemsetAsync(d_ws, 0, (size_t)nseg * (SED + 1) * sizeof(float), stream);
        const int ntiles64 = (nobs + 63) / 64;
        const int gridTok  = (ntiles64 < 2048) ? ntiles64 : 2048;
        tok_scatter_kernel<<<gridTok, 256, 0, stream>>>(
            obs, meta, pix, lch, lplat, otype, offs,
            embed, w1, b1, lng, lnb, w2, b2, bucket,
            sums, cnts, nobs, npix, nbatch);
        dim3 gp((nseg + CG - 1)/CG, 2, 1);
        proj_meancnt_kernel<<<gp, 256, 0, stream>>>(sums, cnts, infill, wp, bp,
                                                    (float*)d_out, nseg);
    }
}

// Round 14
// 621.787 us; speedup vs baseline: 1.1725x; 1.0050x over previous
//
#include <hip/hip_runtime.h>
#include <cstdint>
#include <cstddef>

// Problem constants
#define NCH_CONST 16     // bucket = platform*16 + channel
#define SED 32           // encoded feature dim
#define HID 64           // tokenizer hidden dim
#define MLP_IN 33        // 1 + 28 meta + 4 emb
#define OUTD 512         // projection output dim

#define TILE3 192        // 3 slots per quad: rows s, s+64, s+128

__device__ __forceinline__ void fma4(float4& acc, float xk, float4 wv) {
    acc.x = fmaf(xk, wv.x, acc.x);
    acc.y = fmaf(xk, wv.y, acc.y);
    acc.z = fmaf(xk, wv.z, acc.z);
    acc.w = fmaf(xk, wv.w, acc.w);
}

__device__ __forceinline__ void atomAddF(float* p, float v) {
    unsafeAtomicAdd(p, v);   // native global_atomic_add_f32 (fallback path only)
}

// ---- DPP quad-lane primitives (VALU pipe — __shfl lowers to ds_bpermute on
// the LDS pipe). Literal ctrl only; scalar operands only (R12/R13 lesson:
// never on runtime-indexed aggregates). Proven correct in R13.
__device__ __forceinline__ float qswap1(float v) {  // lane ^= 1 within quad
    return __int_as_float(__builtin_amdgcn_mov_dpp(__float_as_int(v), 0xB1, 0xF, 0xF, true));
}
__device__ __forceinline__ float qswap2(float v) {  // lane ^= 2 within quad
    return __int_as_float(__builtin_amdgcn_mov_dpp(__float_as_int(v), 0x4E, 0xF, 0xF, true));
}
__device__ __forceinline__ int qb0i(int v) {        // bcast quad lane 0
    return __builtin_amdgcn_mov_dpp(v, 0x00, 0xF, 0xF, true);
}

// ===========================================================================
// K0: seg histogram pre-pass.
// ===========================================================================
__global__ __launch_bounds__(256) void seghist_kernel(
    const int* __restrict__ g_pix, const int* __restrict__ g_off,
    int* __restrict__ g_hist, int nobs, int npix, int nbatch)
{
    __shared__ int s_off[32];
    if (threadIdx.x < 32)
        s_off[threadIdx.x] = (threadIdx.x < nbatch) ? g_off[threadIdx.x] : 0x7fffffff;
    __syncthreads();
    const int i = blockIdx.x * 256 + threadIdx.x;
    if (i < nobs) {
        int bidx = 0;
        for (int j = 0; j < nbatch; ++j) bidx += (i >= s_off[j]) ? 1 : 0;
        if (bidx > nbatch - 1) bidx = nbatch - 1;
        atomicAdd(&g_hist[bidx * npix + g_pix[i]], 1);
    }
}

// ===========================================================================
// K1 (R25): R24 structure (proven 388 us: 3 slots/quad, barrier-free
// per-wave ownership, issue-early/write-late staging, weights in LDS,
// packed segbid, rcp-SiLU + rsq-LN) with ONE change: the 15 quad-local
// __shfl ops (12 LN-reduce shfl_xor + 3 pos broadcasts) -> DPP quad_perm
// on the VALU pipe. Removes 15 ds_bpermute per thread-tile from the ~70%-
// occupied LDS pipe + 2 dependent-chain LDS latencies in mu->var->rs.
// ===========================================================================

#define P2S3(xa, xb, xc, K) {                                                  \
    const float4* wr = (const float4*)&s_w1p[(K)*64 + p*16];                   \
    float4 wa = wr[0], wb = wr[1], wc = wr[2], wd = wr[3];                     \
    fma4(hA0, (xa), wa); fma4(hA1, (xa), wb);                                  \
    fma4(hA2, (xa), wc); fma4(hA3, (xa), wd);                                  \
    fma4(hB0, (xb), wa); fma4(hB1, (xb), wb);                                  \
    fma4(hB2, (xb), wc); fma4(hB3, (xb), wd);                                  \
    fma4(hC0, (xc), wa); fma4(hC1, (xc), wb);                                  \
    fma4(hC2, (xc), wc); fma4(hC3, (xc), wd); }

#define P3S3(ha, hb, hc, K) {                                                  \
    const float4* wr = (const float4*)&s_w2s[(K)*32 + p*8];                    \
    float4 wa = wr[0], wb = wr[1];                                             \
    fma4(yA0, (ha), wa); fma4(yA1, (ha), wb);                                  \
    fma4(yB0, (hb), wa); fma4(yB1, (hb), wb);                                  \
    fma4(yC0, (hc), wa); fma4(yC1, (hc), wb); }

#define STG_LOAD(TT) {                                                         \
    const int mA = (((TT) * TILE3) + rowA0) * 28;                              \
    _Pragma("unroll")                                                          \
    for (int g = 0; g < 3; ++g) {                                              \
        const int mb = mA + g * (64*28);                                       \
        _Pragma("unroll")                                                      \
        for (int i = 0; i < 7; ++i) {                                          \
            const int j = mb + lane + (i << 6);                                \
            pfm[g][i] = (j < nmeta) ? g_meta[j] : 0.f;                         \
        }                                                                      \
    }                                                                          \
    if (lane < 48) {                                                           \
        const int rr = rowA0 + ((lane >> 4) << 6) + (lane & 15);               \
        const int gi = (TT) * TILE3 + rr;                                      \
        const bool v = gi < nobs;                                              \
        pf_o = v ? g_obs[gi] : 0.f;                                            \
        const int ot = v ? g_otype[gi] : 0;                                    \
        pf_e = ((const float4*)g_embed)[ot];                                   \
        const int px = v ? g_pix[gi] : 0;                                      \
        const int pl = v ? g_lplat[gi] : 0;                                    \
        const int lc = v ? g_lch[gi] : 0;                                      \
        int bidx = 0;                                                          \
        for (int j2 = 0; j2 < nbatch; ++j2) bidx += (gi >= s_off[j2]) ? 1 : 0; \
        if (bidx > nbatch - 1) bidx = nbatch - 1;                              \
        pf_seg = bidx * npix + px;                                             \
        pf_bid = pl * NCH_CONST + lc;                                          \
        pf_rr = rr;                                                            \
    }                                                                          \
}

#define STG_WRITE() {                                                          \
    _Pragma("unroll")                                                          \
    for (int g = 0; g < 3; ++g) {                                              \
        const int rb = rowA0 + (g << 6);                                       \
        _Pragma("unroll")                                                      \
        for (int i = 0; i < 7; ++i) {                                          \
            const int ii = lane + (i << 6);                                    \
            const int sl = ii / 28, cc = ii - sl * 28;                         \
            s_XH[(rb + sl) * 68 + cc] = pfm[g][i];                             \
        }                                                                      \
    }                                                                          \
    if (lane < 48) {                                                           \
        s_XH[pf_rr * 68 + 32] = pf_o;                                          \
        *(float4*)&s_XH[pf_rr * 68 + 28] = pf_e;                               \
        s_segbid[pf_rr] = pf_seg | (pf_bid << 18);                             \
    }                                                                          \
}

__global__ __launch_bounds__(256, 2) void mlp_encode_kernel(
    const float* __restrict__ g_obs,
    const float* __restrict__ g_meta,
    const int*   __restrict__ g_pix,
    const int*   __restrict__ g_lch,
    const int*   __restrict__ g_lplat,
    const int*   __restrict__ g_otype,
    const int*   __restrict__ g_off,
    const float* __restrict__ g_embed,
    const float* __restrict__ g_w1,
    const float* __restrict__ g_b1,
    const float* __restrict__ g_lng,
    const float* __restrict__ g_lnb,
    const float* __restrict__ g_w2,
    const float* __restrict__ g_b2,
    const float* __restrict__ g_bucket,
    float* __restrict__ g_enc,      // (nobs, 32) SORTED-position encoded rows
    int*   __restrict__ g_cursor,   // (nseg,) = base after scan; bumped here
    int nobs, int npix, int nbatch)
{
    __shared__ __align__(16) float s_w1p[MLP_IN*HID]; // 8448 B, PERMUTED rows
    __shared__ __align__(16) float s_w2s[HID*32];     // shifted, 8192 B
    __shared__ __align__(16) float s_b1[HID];
    __shared__ __align__(16) float s_g[HID];
    __shared__ __align__(16) float s_lb[HID];
    __shared__ __align__(16) float s_b2s[32];         // shifted b2 (c0 = 0)
    __shared__ int   s_off[32];
    __shared__ int   s_segbid[TILE3];                 // seg | (bid<<18)
    __shared__ __align__(16) float s_XH[TILE3*68];    // X(33u)/H(64u) overlay

    const int t = threadIdx.x;

    for (int i = t; i < MLP_IN*HID; i += 256) {
        const int c = i >> 6, j = i & 63;
        const int kp = (c == 32) ? 0 : (c + 1);  // meta c->w1 row c+1; obs(32)->row 0
        s_w1p[i] = g_w1[kp*64 + j];
    }
    for (int i = t; i < HID*32; i += 256) {
        int k = i >> 5, c = i & 31;
        s_w2s[i] = (c == 0) ? 0.0f : g_w2[k*31 + (c-1)];
    }
    if (t < HID) { s_b1[t] = g_b1[t]; s_g[t] = g_lng[t]; s_lb[t] = g_lnb[t]; }
    if (t < 32)  {
        s_b2s[t] = (t == 0) ? 0.0f : g_b2[t-1];
        s_off[t] = (t < nbatch) ? g_off[t] : 0x7fffffff;
    }
    __syncthreads();   // the ONLY barrier

    const int w = t >> 6;        // wave id (0..3)
    const int lane = t & 63;
    const int s = t >> 2;        // slot group; wave w owns s in [16w,16w+16)
    const int p = t & 3;         // part (h[16p..16p+15], enc ch [8p,8p+8))
    const int rowA0 = w << 4;
    const int ntiles = (nobs + TILE3 - 1) / TILE3;
    const int stride = gridDim.x;
    const int nmeta = nobs * 28;

    float pfm[3][7];
    float pf_o = 0.f;
    float4 pf_e = make_float4(0.f, 0.f, 0.f, 0.f);
    int pf_seg = 0, pf_bid = 0, pf_rr = 0;

    int tile = blockIdx.x;
    if (tile < ntiles) {
        STG_LOAD(tile)
        STG_WRITE()
    }

    for (; tile < ntiles; tile += stride) {
        const int nt = tile + stride;
        const bool has_next = nt < ntiles;
        if (has_next) STG_LOAD(nt)

        const int base = tile * TILE3;

        float4 hA0 = ((const float4*)s_b1)[p*4+0];
        float4 hA1 = ((const float4*)s_b1)[p*4+1];
        float4 hA2 = ((const float4*)s_b1)[p*4+2];
        float4 hA3 = ((const float4*)s_b1)[p*4+3];
        float4 hB0 = hA0, hB1 = hA1, hB2 = hA2, hB3 = hA3;
        float4 hC0 = hA0, hC1 = hA1, hC2 = hA2, hC3 = hA3;
        const float* xrowA = &s_XH[s*68];
        const float* xrowB = &s_XH[(s+64)*68];
        const float* xrowC = &s_XH[(s+128)*68];
        const float oA = xrowA[32];
        const float oB = xrowB[32];
        const float oC = xrowC[32];
        #pragma unroll 4
        for (int k4 = 0; k4 < 8; ++k4) {
            const float4 xvA = ((const float4*)xrowA)[k4];
            const float4 xvB = ((const float4*)xrowB)[k4];
            const float4 xvC = ((const float4*)xrowC)[k4];
            const int kb = k4 * 4;
            P2S3(xvA.x, xvB.x, xvC.x, kb+0)
            P2S3(xvA.y, xvB.y, xvC.y, kb+1)
            P2S3(xvA.z, xvB.z, xvC.z, kb+2)
            P2S3(xvA.w, xvB.w, xvC.w, kb+3)
        }
        P2S3(oA, oB, oC, 32)

        // ---- LayerNorm(64) via DPP quad swaps (VALU) + rcp-SiLU ----
        #define HS4(h0,h1,h2,h3) ((h0.x+h0.y+h0.z+h0.w)+(h1.x+h1.y+h1.z+h1.w)+ \
                                  (h2.x+h2.y+h2.z+h2.w)+(h3.x+h3.y+h3.z+h3.w))
        float muA = HS4(hA0,hA1,hA2,hA3);
        float muB = HS4(hB0,hB1,hB2,hB3);
        float muC = HS4(hC0,hC1,hC2,hC3);
        #undef HS4
        muA += qswap1(muA); muB += qswap1(muB); muC += qswap1(muC);
        muA += qswap2(muA); muB += qswap2(muB); muC += qswap2(muC);
        muA *= (1.f/64.f); muB *= (1.f/64.f); muC *= (1.f/64.f);
        #define SQS(hh, mm) ((hh.x-mm)*(hh.x-mm)+(hh.y-mm)*(hh.y-mm)+ \
                             (hh.z-mm)*(hh.z-mm)+(hh.w-mm)*(hh.w-mm))
        float varA = SQS(hA0,muA) + SQS(hA1,muA) + SQS(hA2,muA) + SQS(hA3,muA);
        float varB = SQS(hB0,muB) + SQS(hB1,muB) + SQS(hB2,muB) + SQS(hB3,muB);
        float varC = SQS(hC0,muC) + SQS(hC1,muC) + SQS(hC2,muC) + SQS(hC3,muC);
        #undef SQS
        varA += qswap1(varA); varB += qswap1(varB); varC += qswap1(varC);
        varA += qswap2(varA); varB += qswap2(varB); varC += qswap2(varC);
        const float rsA = __builtin_amdgcn_rsqf(varA*(1.f/64.f) + 1e-5f);
        const float rsB = __builtin_amdgcn_rsqf(varB*(1.f/64.f) + 1e-5f);
        const float rsC = __builtin_amdgcn_rsqf(varC*(1.f/64.f) + 1e-5f);

        const float4* g4 = (const float4*)&s_g[p*16];
        const float4* l4 = (const float4*)&s_lb[p*16];
        float4 ga = g4[0], gb = g4[1], gc = g4[2], gd = g4[3];
        float4 la = l4[0], lb_ = l4[1], lc = l4[2], ld = l4[3];
        // SiLU via v_rcp_f32 (~1 ulp << 1/256 tolerance).
        #define LNSILU(hh, mm, rr, gg, ll) { \
            float v0 = (hh.x - mm) * rr * gg.x + ll.x; \
            float v1 = (hh.y - mm) * rr * gg.y + ll.y; \
            float v2 = (hh.z - mm) * rr * gg.z + ll.z; \
            float v3 = (hh.w - mm) * rr * gg.w + ll.w; \
            hh.x = v0 * __builtin_amdgcn_rcpf(1.f + __expf(-v0)); \
            hh.y = v1 * __builtin_amdgcn_rcpf(1.f + __expf(-v1)); \
            hh.z = v2 * __builtin_amdgcn_rcpf(1.f + __expf(-v2)); \
            hh.w = v3 * __builtin_amdgcn_rcpf(1.f + __expf(-v3)); }
        LNSILU(hA0, muA, rsA, ga, la); LNSILU(hA1, muA, rsA, gb, lb_);
        LNSILU(hA2, muA, rsA, gc, lc); LNSILU(hA3, muA, rsA, gd, ld);
        LNSILU(hB0, muB, rsB, ga, la); LNSILU(hB1, muB, rsB, gb, lb_);
        LNSILU(hB2, muB, rsB, gc, lc); LNSILU(hB3, muB, rsB, gd, ld);
        LNSILU(hC0, muC, rsC, ga, la); LNSILU(hC1, muC, rsC, gb, lb_);
        LNSILU(hC2, muC, rsC, gc, lc); LNSILU(hC3, muC, rsC, gd, ld);
        #undef LNSILU

        float4* hdstA = (float4*)&s_XH[s*68 + p*16];
        hdstA[0] = hA0; hdstA[1] = hA1; hdstA[2] = hA2; hdstA[3] = hA3;
        float4* hdstB = (float4*)&s_XH[(s+64)*68 + p*16];
        hdstB[0] = hB0; hdstB[1] = hB1; hdstB[2] = hB2; hdstB[3] = hB3;
        float4* hdstC = (float4*)&s_XH[(s+128)*68 + p*16];
        hdstC[0] = hC0; hdstC[1] = hC1; hdstC[2] = hC2; hdstC[3] = hC3;

        float4 yA0 = ((const float4*)s_b2s)[p*2+0];
        float4 yA1 = ((const float4*)s_b2s)[p*2+1];
        float4 yB0 = yA0, yB1 = yA1;
        float4 yC0 = yA0, yC1 = yA1;
        const float* hrowA = &s_XH[s*68];
        const float* hrowB = &s_XH[(s+64)*68];
        const float* hrowC = &s_XH[(s+128)*68];
        #pragma unroll 4
        for (int k4 = 0; k4 < 16; ++k4) {
            const float4 hvA = ((const float4*)hrowA)[k4];
            const float4 hvB = ((const float4*)hrowB)[k4];
            const float4 hvC = ((const float4*)hrowC)[k4];
            const int kb = k4 * 4;
            P3S3(hvA.x, hvB.x, hvC.x, kb+0)
            P3S3(hvA.y, hvB.y, hvC.y, kb+1)
            P3S3(hvA.z, hvB.z, hvC.z, kb+2)
            P3S3(hvA.w, hvB.w, hvC.w, kb+3)
        }

        const int giA = base + s;
        const int giB = giA + 64;
        const int giC = giA + 128;
        int posA = 0, posB = 0, posC = 0;
        if (p == 0) {
            if (giA < nobs) posA = atomicAdd(&g_cursor[s_segbid[s] & 0x3FFFF], 1);
            if (giB < nobs) posB = atomicAdd(&g_cursor[s_segbid[s+64] & 0x3FFFF], 1);
            if (giC < nobs) posC = atomicAdd(&g_cursor[s_segbid[s+128] & 0x3FFFF], 1);
        }
        // DPP quad-broadcast from lane 0 of each quad (VALU, not ds_bpermute)
        posA = qb0i(posA);
        posB = qb0i(posB);
        posC = qb0i(posC);

        if (giA < nobs) {
            const float4* bkt = (const float4*)g_bucket + (s_segbid[s] >> 18)*8;
            float4 ba = bkt[p*2], bb = bkt[p*2+1];
            if (p == 0) yA0.x = oA;
            float4 r0 = make_float4(yA0.x+ba.x, yA0.y+ba.y, yA0.z+ba.z, yA0.w+ba.w);
            float4 r1 = make_float4(yA1.x+bb.x, yA1.y+bb.y, yA1.z+bb.z, yA1.w+bb.w);
            float4* dst = (float4*)(g_enc + (size_t)posA * SED + p*8);
            dst[0] = r0; dst[1] = r1;
        }
        if (giB < nobs) {
            const float4* bkt = (const float4*)g_bucket + (s_segbid[s+64] >> 18)*8;
            float4 ba = bkt[p*2], bb = bkt[p*2+1];
            if (p == 0) yB0.x = oB;
            float4 r0 = make_float4(yB0.x+ba.x, yB0.y+ba.y, yB0.z+ba.z, yB0.w+ba.w);
            float4 r1 = make_float4(yB1.x+bb.x, yB1.y+bb.y, yB1.z+bb.z, yB1.w+bb.w);
            float4* dst = (float4*)(g_enc + (size_t)posB * SED + p*8);
            dst[0] = r0; dst[1] = r1;
        }
        if (giC < nobs) {
            const float4* bkt = (const float4*)g_bucket + (s_segbid[s+128] >> 18)*8;
            float4 ba = bkt[p*2], bb = bkt[p*2+1];
            if (p == 0) yC0.x = oC;
            float4 r0 = make_float4(yC0.x+ba.x, yC0.y+ba.y, yC0.z+ba.z, yC0.w+ba.w);
            float4 r1 = make_float4(yC1.x+bb.x, yC1.y+bb.y, yC1.z+bb.z, yC1.w+bb.w);
            float4* dst = (float4*)(g_enc + (size_t)posC * SED + p*8);
            dst[0] = r0; dst[1] = r1;
        }

        if (has_next) STG_WRITE()
    }
}

// ---------------------------------------------------------------------------
// K2a: per-block exclusive scan of hist (512 elems/block), RAW block totals
// ---------------------------------------------------------------------------
__global__ __launch_bounds__(256) void scan_block_kernel(
    const int* __restrict__ g_hist, int* __restrict__ g_base,
    int* __restrict__ g_btot, int n)
{
    __shared__ int s[512];
    const int t  = threadIdx.x;
    const int i0 = blockIdx.x * 512 + t;
    const int i1 = i0 + 256;
    const int o0 = (i0 < n) ? g_hist[i0] : 0;
    const int o1 = (i1 < n) ? g_hist[i1] : 0;
    s[t] = o0; s[t+256] = o1;
    __syncthreads();
    for (int off = 1; off < 512; off <<= 1) {
        int a = (t >= off) ? s[t - off] : 0;
        int b = s[t + 256 - off];
        __syncthreads();
        s[t] += a; s[t+256] += b;
        __syncthreads();
    }
    if (i0 < n) g_base[i0] = s[t] - o0;
    if (i1 < n) g_base[i1] = s[t+256] - o1;
    if (t == 255) g_btot[blockIdx.x] = s[511];
}

// ---------------------------------------------------------------------------
// K2b: add_spine with INLINE spine prefix (kills scan_spine launch).
// ---------------------------------------------------------------------------
__global__ __launch_bounds__(256) void add_spine_kernel(
    int* __restrict__ g_base, int* __restrict__ g_cursor,
    const int* __restrict__ g_btot, int nblocksScan, int n)
{
    __shared__ int s[256];
    const int t = threadIdx.x;
    const int sb = blockIdx.x >> 1;       // scan-block covering this add-block
    s[t] = (t < sb && t < nblocksScan) ? g_btot[t] : 0;
    __syncthreads();
    for (int off = 128; off > 0; off >>= 1) {
        if (t < off) s[t] += s[t + off];
        __syncthreads();
    }
    const int prefix = s[0];
    const int i = blockIdx.x * 256 + t;
    if (i < n) {
        int v = g_base[i] + prefix;
        g_base[i] = v;
        g_cursor[i] = v;
    }
}

// ---------------------------------------------------------------------------
// K4+K5 fused (R21 proj, PROVEN — R22's transposed variant regressed +81 us;
// compiler LICM already hoists the it-invariant w reads): reduce 16 segments
// -> s_cell (threads 0-127) while threads 128-255 stage wp into LDS; then
// all 256 threads project the 16x512 output tile.
// ---------------------------------------------------------------------------
#define CG 16
__device__ __forceinline__ void add4(float4& a, float4 b) {
    a.x += b.x; a.y += b.y; a.z += b.z; a.w += b.w;
}

__global__ __launch_bounds__(256) void reduce_proj_kernel(
    const float* __restrict__ g_enc,
    const int*   __restrict__ g_base,
    const int*   __restrict__ g_hist,
    const float* __restrict__ g_infill,
    const float* __restrict__ g_wp,
    const float* __restrict__ g_bp,
    float* __restrict__ g_out,
    int nseg)
{
    __shared__ __align__(16) float s_wp[SED*OUTD];    // 65536 B
    __shared__ __align__(16) float s_cell[CG][SED];   // 2048 B

    const int t = threadIdx.x;
    const int cell0 = blockIdx.x * CG;

    if (t < 128) {
        // ---- reduce phase: 16 segs x 8 lanes ----
        const int gl = t >> 3;            // local segment 0..15
        const int c4 = t & 7;             // float4 column
        const int g  = cell0 + gl;
        float4 r = make_float4(0,0,0,0);
        if (g < nseg) {
            const int b = g_base[g];
            const int n = g_hist[g];
            const float4* src = (const float4*)g_enc + (size_t)b * 8 + c4;
            float4 a0 = make_float4(0,0,0,0), a1 = a0, a2 = a0, a3 = a0;
            int j = 0;
            for (; j + 3 < n; j += 4) {
                float4 v0 = src[(size_t)(j+0)*8];
                float4 v1 = src[(size_t)(j+1)*8];
                float4 v2 = src[(size_t)(j+2)*8];
                float4 v3 = src[(size_t)(j+3)*8];
                add4(a0, v0); add4(a1, v1); add4(a2, v2); add4(a3, v3);
            }
            for (; j < n; ++j) add4(a0, src[(size_t)j*8]);
            add4(a0, a1); add4(a2, a3); add4(a0, a2);
            if (n > 0) {
                const float inv = 1.f / (float)n;
                r = make_float4(a0.x*inv, a0.y*inv, a0.z*inv, a0.w*inv);
            } else {
                r = ((const float4*)g_infill)[c4];
            }
        }
        *(float4*)&s_cell[gl][c4*4] = r;
    } else {
        // ---- wp staging phase: 128 threads copy 4096 float4 (64 KB) ----
        const int t2 = t - 128;
        #pragma unroll
        for (int i = 0; i < 32; ++i) {
            const int idx = t2 + i*128;
            ((float4*)s_wp)[idx] = ((const float4*)g_wp)[idx];
        }
    }
    __syncthreads();

    // ---- proj phase: 16 cells x 128 float4 cols = 2048 float4; 8/thread ----
    #pragma unroll
    for (int it = 0; it < 8; ++it) {
        const int idx4 = it*256 + t;
        const int g  = idx4 >> 7;         // 0..15
        const int c4 = idx4 & 127;        // 0..127
        if (cell0 + g < nseg) {
            float4 acc = ((const float4*)g_bp)[c4];
            #pragma unroll
            for (int k = 0; k < SED; ++k) {
                const float cg = s_cell[g][k];
                const float4 w = ((const float4*)s_wp)[k*128 + c4];
                acc.x += cg*w.x; acc.y += cg*w.y; acc.z += cg*w.z; acc.w += cg*w.w;
            }
            ((float4*)g_out)[(size_t)(cell0 + g)*128 + c4] = acc;
        }
    }
}

// ===========================================================================
// FALLBACK (ws too small or nseg too large for packed segbid): atomic path
// ===========================================================================
__global__ __launch_bounds__(256, 2) void tok_scatter_kernel(
    const float* __restrict__ g_obs, const float* __restrict__ g_meta,
    const int* __restrict__ g_pix, const int* __restrict__ g_lch,
    const int* __restrict__ g_lplat, const int* __restrict__ g_otype,
    const int* __restrict__ g_off, const float* __restrict__ g_embed,
    const float* __restrict__ g_w1, const float* __restrict__ g_b1,
    const float* __restrict__ g_lng, const float* __restrict__ g_lnb,
    const float* __restrict__ g_w2, const float* __restrict__ g_b2,
    const float* __restrict__ g_bucket,
    float* __restrict__ g_sums, float* __restrict__ g_cnts,
    int nobs, int npix, int nbatch)
{
    __shared__ __align__(16) float s_w1[MLP_IN*HID];
    __shared__ __align__(16) float s_w2s[HID*32];
    __shared__ __align__(16) float s_b1[HID], s_g[HID], s_lb[HID];
    __shared__ __align__(16) float s_b2s[32];
    __shared__ int   s_off[32];
    __shared__ __align__(16) float s_X[64*34];
    __shared__ __align__(16) float s_H[64*68];

    const int t = threadIdx.x;
    for (int i = t; i < MLP_IN*HID; i += 256) s_w1[i] = g_w1[i];
    for (int i = t; i < HID*32; i += 256) {
        int k = i >> 5, c = i & 31;
        s_w2s[i] = (c == 0) ? 0.0f : g_w2[k*31 + (c-1)];
    }
    if (t < HID) { s_b1[t] = g_b1[t]; s_g[t] = g_lng[t]; s_lb[t] = g_lnb[t]; }
    if (t < 32)  {
        s_b2s[t] = (t == 0) ? 0.0f : g_b2[t-1];
        s_off[t] = (t < nbatch) ? g_off[t] : 0x7fffffff;
    }
    __syncthreads();

    const int s = t >> 2;
    const int p = t & 3;
    const int ntiles = (nobs + 63) >> 6;

    for (int tile = blockIdx.x; tile < ntiles; tile += gridDim.x) {
        const int base = tile << 6;
        for (int j = t; j < 64*28; j += 256) {
            int sl = j / 28, c = j - sl*28;
            float v = ((base + sl) < nobs) ? g_meta[(size_t)base*28 + j] : 0.f;
            s_X[sl*34 + 1 + c] = v;
        }
        if (t < 64) {
            const int gi = base + t;
            float o = 0.f; int ot = 0;
            if (gi < nobs) { o = g_obs[gi]; ot = g_otype[gi]; }
            s_X[t*34 + 0] = o;
            float4 e = ((const float4*)g_embed)[ot];
            s_X[t*34 + 29] = e.x; s_X[t*34 + 30] = e.y;
            s_X[t*34 + 31] = e.z; s_X[t*34 + 32] = e.w;
        }
        __syncthreads();

        float4 h0 = ((const float4*)s_b1)[p*4+0];
        float4 h1 = ((const float4*)s_b1)[p*4+1];
        float4 h2 = ((const float4*)s_b1)[p*4+2];
        float4 h3 = ((const float4*)s_b1)[p*4+3];
        const float* xrow = &s_X[s*34];
        #pragma unroll 2
        for (int k = 0; k < MLP_IN; ++k) {
            const float xk = xrow[k];
            const float4* wr = (const float4*)&s_w1[k*64 + p*16];
            float4 wa = wr[0], wb = wr[1], wc = wr[2], wd = wr[3];
            fma4(h0, xk, wa); fma4(h1, xk, wb);
            fma4(h2, xk, wc); fma4(h3, xk, wd);
        }
        float mu = (h0.x+h0.y+h0.z+h0.w) + (h1.x+h1.y+h1.z+h1.w)
                 + (h2.x+h2.y+h2.z+h2.w) + (h3.x+h3.y+h3.z+h3.w);
        mu += __shfl_xor(mu, 1, 64);
        mu += __shfl_xor(mu, 2, 64);
        mu *= (1.f/64.f);
        float var =
            (h0.x-mu)*(h0.x-mu)+(h0.y-mu)*(h0.y-mu)+(h0.z-mu)*(h0.z-mu)+(h0.w-mu)*(h0.w-mu)
          + (h1.x-mu)*(h1.x-mu)+(h1.y-mu)*(h1.y-mu)+(h1.z-mu)*(h1.z-mu)+(h1.w-mu)*(h1.w-mu)
          + (h2.x-mu)*(h2.x-mu)+(h2.y-mu)*(h2.y-mu)+(h2.z-mu)*(h2.z-mu)+(h2.w-mu)*(h2.w-mu)
          + (h3.x-mu)*(h3.x-mu)+(h3.y-mu)*(h3.y-mu)+(h3.z-mu)*(h3.z-mu)+(h3.w-mu)*(h3.w-mu);
        var += __shfl_xor(var, 1, 64);
        var += __shfl_xor(var, 2, 64);
        var *= (1.f/64.f);
        const float rs = rsqrtf(var + 1e-5f);
        const float4* g4 = (const float4*)&s_g[p*16];
        const float4* l4 = (const float4*)&s_lb[p*16];
        float4 ga = g4[0], gb = g4[1], gc = g4[2], gd = g4[3];
        float4 la = l4[0], lb_ = l4[1], lc = l4[2], ld = l4[3];
        #define LNSILU(hh, gg, ll) { \
            float v0 = (hh.x - mu) * rs * gg.x + ll.x; \
            float v1 = (hh.y - mu) * rs * gg.y + ll.y; \
            float v2 = (hh.z - mu) * rs * gg.z + ll.z; \
            float v3 = (hh.w - mu) * rs * gg.w + ll.w; \
            hh.x = v0 / (1.f + __expf(-v0)); \
            hh.y = v1 / (1.f + __expf(-v1)); \
            hh.z = v2 / (1.f + __expf(-v2)); \
            hh.w = v3 / (1.f + __expf(-v3)); }
        LNSILU(h0, ga, la); LNSILU(h1, gb, lb_);
        LNSILU(h2, gc, lc); LNSILU(h3, gd, ld);
        #undef LNSILU
        float4* hdst = (float4*)&s_H[s*68 + p*16];
        hdst[0] = h0; hdst[1] = h1; hdst[2] = h2; hdst[3] = h3;
        __syncthreads();

        float4 y0 = ((const float4*)s_b2s)[p*2+0];
        float4 y1 = ((const float4*)s_b2s)[p*2+1];
        const float* hrow = &s_H[s*68];
        #pragma unroll 2
        for (int k = 0; k < HID; ++k) {
            const float hk = hrow[k];
            const float4* wr = (const float4*)&s_w2s[k*32 + p*8];
            float4 wa = wr[0], wb = wr[1];
            fma4(y0, hk, wa); fma4(y1, hk, wb);
        }
        const int gi = base + s;
        if (gi < nobs) {
            int bidx = 0;
            for (int j2 = 0; j2 < nbatch; ++j2) bidx += (gi >= s_off[j2]) ? 1 : 0;
            if (bidx > nbatch - 1) bidx = nbatch - 1;
            const int seg = bidx * npix + g_pix[gi];
            const int bid = g_lplat[gi] * NCH_CONST + g_lch[gi];
            const float4* bkt = (const float4*)g_bucket + bid*8;
            float4 ba = bkt[p*2], bb = bkt[p*2+1];
            if (p == 0) y0.x = s_X[s*34];
            float* sp = g_sums + (size_t)seg * SED + p*8;
            atomAddF(&sp[0], y0.x+ba.x); atomAddF(&sp[1], y0.y+ba.y);
            atomAddF(&sp[2], y0.z+ba.z); atomAddF(&sp[3], y0.w+ba.w);
            atomAddF(&sp[4], y1.x+bb.x); atomAddF(&sp[5], y1.y+bb.y);
            atomAddF(&sp[6], y1.z+bb.z); atomAddF(&sp[7], y1.w+bb.w);
            if (p == 0) atomAddF(&g_cnts[seg], 1.0f);
        }
        __syncthreads();
    }
}

__global__ __launch_bounds__(256) void proj_meancnt_kernel(
    const float* __restrict__ g_sums, const float* __restrict__ g_cnts,
    const float* __restrict__ g_infill, const float* __restrict__ g_wp,
    const float* __restrict__ g_bp, float* __restrict__ g_out, int nseg)
{
    __shared__ __align__(16) float s_wp[SED*256];
    __shared__ __align__(16) float s_cell[CG][SED];
    const int t = threadIdx.x;
    const int half = blockIdx.y;
    const int cell0 = blockIdx.x * CG;
    for (int i = t; i < SED*64; i += 256) {
        int k = i >> 6, c4 = i & 63;
        ((float4*)s_wp)[k*64 + c4] = ((const float4*)g_wp)[k*128 + half*64 + c4];
    }
    for (int i = t; i < CG*SED; i += 256) {
        int g = i >> 5, c = i & 31;
        float cnt = g_cnts[cell0 + g];
        float s   = g_sums[(size_t)(cell0 + g)*SED + c];
        s_cell[g][c] = (cnt > 0.f) ? (s / fmaxf(cnt, 1.f)) : g_infill[c];
    }
    __syncthreads();
    #pragma unroll
    for (int it = 0; it < 4; ++it) {
        int idx4 = it*256 + t;
        int g  = idx4 >> 6;
        int c4 = idx4 & 63;
        float4 acc = ((const float4*)g_bp)[half*64 + c4];
        #pragma unroll
        for (int k = 0; k < SED; ++k) {
            float cg = s_cell[g][k];
            float4 w = ((const float4*)s_wp)[k*64 + c4];
            acc.x += cg*w.x; acc.y += cg*w.y; acc.z += cg*w.z; acc.w += cg*w.w;
        }
        ((float4*)g_out)[(size_t)(cell0 + g)*128 + half*64 + c4] = acc;
    }
}

// ===========================================================================
extern "C" void kernel_launch(void* const* d_in, const int* in_sizes, int n_in,
                              void* d_out, int out_size, void* d_ws, size_t ws_size,
                              hipStream_t stream)
{
    const float* obs    = (const float*)d_in[0];
    const float* meta   = (const float*)d_in[1];
    const int*   pix    = (const int*)d_in[2];
    const int*   lch    = (const int*)d_in[3];
    const int*   lplat  = (const int*)d_in[4];
    const int*   otype  = (const int*)d_in[5];
    const int*   offs   = (const int*)d_in[6];
    const float* embed  = (const float*)d_in[8];
    const float* w1     = (const float*)d_in[9];
    const float* b1     = (const float*)d_in[10];
    const float* lng    = (const float*)d_in[11];
    const float* lnb    = (const float*)d_in[12];
    const float* w2     = (const float*)d_in[13];
    const float* b2     = (const float*)d_in[14];
    const float* bucket = (const float*)d_in[15];
    const float* infill = (const float*)d_in[16];
    const float* wp     = (const float*)d_in[17];
    const float* bp     = (const float*)d_in[18];

    const int nobs   = in_sizes[0];
    const int nbatch = in_sizes[6];
    const int npix   = out_size / (nbatch * OUTD);
    const int nseg   = nbatch * npix;

    // ---- workspace layout (bytes) ----
    char* w = (char*)d_ws;
    size_t off = 0;
    int*   hist    = (int*)(w + off);   off += (size_t)nseg * 4;
    int*   base    = (int*)(w + off);   off += (size_t)nseg * 4;
    int*   cursor  = (int*)(w + off);   off += (size_t)nseg * 4;
    int*   btot    = (int*)(w + off);   off += 4096;
    float* enc     = (float*)(w + off); off += (size_t)nobs * SED * 4;
    const size_t need = off;

    const int ntiles     = (nobs + TILE3 - 1) / TILE3;
    const int gridMlp    = (ntiles < 2048) ? ntiles : 2048;
    const int blocksScan = (nseg + 511) / 512;   // must be <= 256

    if (ws_size >= need && blocksScan <= 256 && nseg <= (1 << 18)) {
        // ---- fast path: hist -> scan -> sorted-write MLP -> fused reduce+proj
        hipMemsetAsync(hist, 0, (size_t)nseg * 4, stream);

        seghist_kernel<<<(nobs + 255)/256, 256, 0, stream>>>(
            pix, offs, hist, nobs, npix, nbatch);

        scan_block_kernel<<<blocksScan, 256, 0, stream>>>(hist, base, btot, nseg);
        add_spine_kernel<<<(nseg + 255)/256, 256, 0, stream>>>(
            base, cursor, btot, blocksScan, nseg);

        mlp_encode_kernel<<<gridMlp, 256, 0, stream>>>(
            obs, meta, pix, lch, lplat, otype, offs,
            embed, w1, b1, lng, lnb, w2, b2, bucket,
            enc, cursor, nobs, npix, nbatch);

        reduce_proj_kernel<<<(nseg + CG - 1)/CG, 256, 0, stream>>>(
            enc, base, hist, infill, wp, bp, (float*)d_out, nseg);
    } else {
        // ---------------- fallback: atomic path ----------------
        float* sums = (float*)d_ws;
        float* cnts = sums + (size_t)nseg * SED;
        hipMemsetAsync(d_ws, 0, (size_t)nseg * (SED + 1) * sizeof(float), stream);
        const int ntiles64 = (nobs + 63) / 64;
        const int gridTok  = (ntiles64 < 2048) ? ntiles64 : 2048;
        tok_scatter_kernel<<<gridTok, 256, 0, stream>>>(
            obs, meta, pix, lch, lplat, otype, offs,
            embed, w1, b1, lng, lnb, w2, b2, bucket,
            sums, cnts, nobs, npix, nbatch);
        dim3 gp((nseg + CG - 1)/CG, 2, 1);
        proj_meancnt_kernel<<<gp, 256, 0, stream>>>(sums, cnts, infill, wp, bp,
                                                    (float*)d_out, nseg);
    }
}